// Round 6
// baseline (2611.384 us; speedup 1.0000x reference)
//
#include <hip/hip_runtime.h>
#include <math.h>

// GraphEncoder v13 = v10 (passed, lean phase ~215us) + ego3 register fix.
// Six-round synthesis: v7 fat phase 276us; lean phase 215us; fused ego3 is
// the right structure but spilled (VGPR 256, 500MB scratch traffic) because
// the fully-unrolled scores e-loop hoisted 175 independent global at-loads
// and the j-loop software-pipelined the 625-FMA matvec across relations.
// v13: #pragma unroll 1 on both loops; nothing else changed vs v10.

#define KF 2
#define DK 25
#define DD 50
#define PS 52   // padded P/z row stride: 208 B = 13 float4
#define ITERS 4
#define WPB 4

static __device__ __forceinline__ float leakyf(float x) { return x > 0.f ? x : 0.2f * x; }

// tanh via exp-based: rel err ~1e-6, monotone, saturates correctly.
static __device__ __forceinline__ float fast_tanhf(float x) {
    float e = __expf(2.f * x);
    return 1.f - 2.f * __builtin_amdgcn_rcpf(e + 1.f);
}

// at[e] is [2][50]: factor k at a+k*50; 0..24 row-side, 25..49 col-side.
static __device__ __forceinline__ float2 score_row50(const float* p, const float* a) {
    float s0 = 0.f, s1 = 0.f;
    #pragma unroll
    for (int f = 0; f < DK; ++f) {
        s0 = fmaf(p[f],      a[f],      s0);
        s1 = fmaf(p[DK + f], a[50 + f], s1);
    }
    return make_float2(s0, s1);
}
static __device__ __forceinline__ float2 score_col50(const float* p, const float* a) {
    float s0 = 0.f, s1 = 0.f;
    #pragma unroll
    for (int f = 0; f < DK; ++f) {
        s0 = fmaf(p[f],      a[25 + f], s0);
        s1 = fmaf(p[DK + f], a[75 + f], s1);
    }
    return make_float2(s0, s1);
}

// ---------------- fac ----------------
struct FacArgs { const float* emb[8]; float* P[8]; const float* Wtk; int base[9]; };

__global__ void fac_kernel(FacArgs A) {
    int g = blockIdx.x * blockDim.x + threadIdx.x;
    if (g >= A.base[8]) return;
    int ty = 0;
    while (g >= A.base[ty + 1]) ++ty;
    int node = g - A.base[ty];
    const float* er = A.emb[ty] + (size_t)node * DD;
    const float* Wt = A.Wtk + (size_t)ty * KF * DD * DK;
    float x[DD];
    #pragma unroll
    for (int d = 0; d < DD; ++d) x[d] = er[d];
    float out[DD];
    #pragma unroll
    for (int k = 0; k < KF; ++k) {
        const float* Wk = Wt + k * DD * DK;
        float nrm = 0.f;
        for (int f = 0; f < DK; ++f) {
            float acc = 0.f;
            for (int d = 0; d < DD; ++d) acc = fmaf(x[d], Wk[d * DK + f], acc);
            acc = leakyf(acc);
            out[k * DK + f] = acc;
            nrm = fmaf(acc, acc, nrm);
        }
        float inv = 1.f / fmaxf(sqrtf(nrm), 1e-12f);
        for (int f = 0; f < DK; ++f) out[k * DK + f] *= inv;
    }
    float* Pr = A.P[ty] + (size_t)node * PS;
    #pragma unroll
    for (int j = 0; j < DD; ++j) Pr[j] = out[j];
    Pr[50] = 0.f; Pr[51] = 0.f;
}

// ---------------- flat CSR build ----------------
struct EdgeArgs {
    const int* rows[8]; const int* cols[8];
    int* cnt;                  // [totalRows] global-row counts -> rowptr
    unsigned short* colind;    // [totE] flat
    int ebase[9];
    int rowbase[8];
};

__global__ void hist_kernel(EdgeArgs A) {
    int g = blockIdx.x * blockDim.x + threadIdx.x;
    if (g >= A.ebase[8]) return;
    int rel = 0;
    while (g >= A.ebase[rel + 1]) ++rel;
    int e = g - A.ebase[rel];
    atomicAdd(&A.cnt[A.rowbase[rel] + A.rows[rel][e]], 1);
}

// 3-kernel hierarchical exclusive scan over cnt[0..n)
__global__ __launch_bounds__(1024) void scan_part_kernel(int* a, int n, int* bsum) {
    __shared__ int lds[1024];
    int tid = threadIdx.x;
    int i = blockIdx.x * 1024 + tid;
    int v = (i < n) ? a[i] : 0;
    lds[tid] = v;
    __syncthreads();
    int x = v;
    for (int off = 1; off < 1024; off <<= 1) {
        int y = (tid >= off) ? lds[tid - off] : 0;
        __syncthreads();
        x += y;
        lds[tid] = x;
        __syncthreads();
    }
    if (i < n) a[i] = x - v;              // exclusive within chunk
    if (tid == 1023) bsum[blockIdx.x] = x; // chunk total
}

__global__ __launch_bounds__(1024) void scan_bsum_kernel(int* bsum, int nb) {
    __shared__ int lds[1024];
    int tid = threadIdx.x;
    int v = (tid < nb) ? bsum[tid] : 0;
    lds[tid] = v;
    __syncthreads();
    int x = v;
    for (int off = 1; off < 1024; off <<= 1) {
        int y = (tid >= off) ? lds[tid - off] : 0;
        __syncthreads();
        x += y;
        lds[tid] = x;
        __syncthreads();
    }
    if (tid < nb) bsum[tid] = x - v;      // exclusive chunk offsets
}

__global__ __launch_bounds__(1024) void add_off_kernel(int* a, int n, const int* bsum) {
    int i = blockIdx.x * 1024 + threadIdx.x;
    if (i < n) a[i] += bsum[blockIdx.x];
}

// scatter bumps cnt in place; afterwards cnt[w] == inclusive end of global row w.
__global__ void scatter_kernel(EdgeArgs A) {
    int g = blockIdx.x * blockDim.x + threadIdx.x;
    if (g >= A.ebase[8]) return;
    int rel = 0;
    while (g >= A.ebase[rel + 1]) ++rel;
    int e = g - A.ebase[rel];
    int p = atomicAdd(&A.cnt[A.rowbase[rel] + A.rows[rel][e]], 1);
    A.colind[p] = (unsigned short)A.cols[rel][e];
}

// ---------------- sb init for static relations 2..7 ----------------
struct SbArgs { const float* Pb[6]; const float* at[6]; float2* sb[6]; int base[7]; };

__global__ void sb_kernel(SbArgs A) {
    int g = blockIdx.x * blockDim.x + threadIdx.x;
    if (g >= A.base[6]) return;
    int rel = 0;
    while (g >= A.base[rel + 1]) ++rel;
    int c = g - A.base[rel];
    const float* p = A.Pb[rel] + (size_t)c * PS;
    A.sb[rel][c] = score_col50(p, A.at[rel]);
}

// ---------------- score01: initial sa (all rels) + sb0/sb1 ----------------
struct ScoreArgs {
    const float* P0; const float* P1;
    const float* at;
    float2* sa[8]; float2* sb0; float2* sb1;
    int n0, n1;
};

__global__ void score01_kernel(ScoreArgs A) {
    int g = blockIdx.x * blockDim.x + threadIdx.x;
    if (g >= A.n0 + A.n1) return;
    if (g < A.n0) {
        const float* p = A.P0 + (size_t)g * PS;
        float pr[DD];
        #pragma unroll
        for (int j = 0; j < DD; ++j) pr[j] = p[j];
        A.sa[0][g] = score_row50(pr, A.at + 0);
        A.sb1[g]   = score_col50(pr, A.at + 100);
    } else {
        int node = g - A.n0;
        const float* p = A.P1 + (size_t)node * PS;
        float pr[DD];
        #pragma unroll
        for (int j = 0; j < DD; ++j) pr[j] = p[j];
        #pragma unroll
        for (int e = 1; e < 8; ++e) A.sa[e][node] = score_row50(pr, A.at + e * 100);
        A.sb0[node] = score_col50(pr, A.at + 0);
    }
}

// ---------------- fused phase (lean: gather + softmax-normalize only) ----------------
struct PhaseArgs {
    const int* rowptr;               // [totalRows] inclusive ends (flat)
    const unsigned short* colind;    // flat
    const float* Pb[8];
    const float2* sa[8]; const float2* sb[8];
    float* z[8];                     // zl rows, PS stride
    int rowbase[9];
};

__global__ __launch_bounds__(WPB * 64) void phase_kernel(PhaseArgs A, int totalRows) {
    int wave = blockIdx.x * WPB + (threadIdx.x >> 6);
    int lane = threadIdx.x & 63;
    if (wave >= totalRows) return;
    int rel = 0;
    while (wave >= A.rowbase[rel + 1]) ++rel;
    int u = wave - A.rowbase[rel];

    const unsigned short* colind = A.colind;
    const float* Pb = A.Pb[rel];
    const float2* sb = A.sb[rel];
    float2 h = A.sa[rel][u];
    int beg = wave ? A.rowptr[wave - 1] : 0;
    int end = A.rowptr[wave];

    int grp4 = lane >> 4, sub4 = lane & 15;
    bool ld = sub4 < 13;   // P row is 13 float4; reading 16 touches a 5th line
    float ssum = 0.f;
    float4 a4 = make_float4(0.f, 0.f, 0.f, 0.f);

    for (int base = beg; base < end; base += 64) {
        int idx = base + lane;
        bool vld = idx < end;
        int cb = vld ? (int)colind[idx] : 0;
        float evl = 0.f;
        if (vld) {
            float2 sc = sb[cb];
            evl = __expf(0.5f * (fmaxf(h.x + sc.x, 0.f) + fmaxf(h.y + sc.y, 0.f)));
        }
        ssum += evl;
        int nb = min(64, end - base);
        #pragma unroll 2
        for (int t = 0; t < nb; t += 4) {
            int srcl = t + grp4;
            int c = __shfl(cb, srcl);
            float ev = __shfl(evl, srcl);
            if (ld) {
                const float4* pc = (const float4*)(Pb + (size_t)c * PS);
                float4 v = pc[sub4];
                a4.x = fmaf(ev, v.x, a4.x);
                a4.y = fmaf(ev, v.y, a4.y);
                a4.z = fmaf(ev, v.z, a4.z);
                a4.w = fmaf(ev, v.w, a4.w);
            }
        }
    }
    #pragma unroll
    for (int off = 32; off >= 16; off >>= 1) {
        a4.x += __shfl_xor(a4.x, off);
        a4.y += __shfl_xor(a4.y, off);
        a4.z += __shfl_xor(a4.z, off);
        a4.w += __shfl_xor(a4.w, off);
    }
    #pragma unroll
    for (int off = 32; off; off >>= 1) ssum += __shfl_xor(ssum, off);

    int src = lane >> 2;
    float fx = __shfl(a4.x, src), fy = __shfl(a4.y, src);
    float fz = __shfl(a4.z, src), fw = __shfl(a4.w, src);
    float za = (lane & 1) ? ((lane & 2) ? fw : fy) : ((lane & 2) ? fz : fx);

    float inv = (ssum > 0.f) ? (1.f / ssum) : 0.f;
    if (lane < DD) A.z[rel][(size_t)u * PS + lane] = leakyf(za * inv);
}

// ---------------- ego3: per-(node,factor) thread; 25-wide frame ----------------
// Thread t -> node t>>1, factor k=t&1. Cross-factor r-softmax via __shfl_xor 1.
// unroll-1 on the j-loop (no cross-relation pipelining) and on the scores
// e-loop (<=25 at-loads in flight, not 175) keeps the frame ~140 VGPR.
struct Ego3Args {
    float* P0; float* P1;
    const float* zz[8];              // zl rows, PS stride
    const float* W;                  // [25][25]
    const float* q;                  // [8][25]
    const float* at;                 // [8][2][50]
    float* sa[8]; float* sb0; float* sb1;   // as float*, component k at 2*node+k
    float* outp;                     // non-null on last iteration: [n0+n1][50]
    int n0, n1;
};

__global__ __launch_bounds__(256) void ego3_kernel(Ego3Args A) {
    __shared__ float Ws[DK * DK];
    for (int i = threadIdx.x; i < DK * DK; i += blockDim.x) Ws[i] = A.W[i];
    __syncthreads();
    int t = blockIdx.x * blockDim.x + threadIdx.x;
    int gnode = t >> 1;
    int k = t & 1;
    if (gnode >= A.n0 + A.n1) return;
    bool is0 = gnode < A.n0;
    int node = is0 ? gnode : gnode - A.n0;
    float* Pr = (is0 ? A.P0 : A.P1) + (size_t)node * PS + k * DK;

    float acc[DK];
    #pragma unroll
    for (int f = 0; f < DK; ++f) acc[f] = Pr[f];

    int jbeg = is0 ? 0 : 1, jend = is0 ? 1 : 8;
    #pragma unroll 1
    for (int j = jbeg; j < jend; ++j) {
        const float* zr = A.zz[j] + (size_t)node * PS + k * DK;
        float zl[DK];
        #pragma unroll
        for (int d = 0; d < DK; ++d) zl[d] = zr[d];
        const float* qv = A.q + (size_t)j * DK;
        float ov[DK];
        float th = 0.f;
        #pragma unroll
        for (int f = 0; f < DK; ++f) {
            float a = 0.f;
            #pragma unroll
            for (int d = 0; d < DK; ++d) a = fmaf(zl[d], Ws[d * DK + f], a);
            ov[f] = a;
            th = fmaf(fast_tanhf(a), qv[f], th);
        }
        float tho = __shfl_xor(th, 1);
        float m = fmaxf(th, tho);
        float es = __expf(th - m), eo = __expf(tho - m);
        float r = es * __builtin_amdgcn_rcpf(es + eo);
        #pragma unroll
        for (int f = 0; f < DK; ++f) acc[f] = fmaf(ov[f], r, acc[f]);
    }

    // l2norm over this factor's 25 components, store new P half-row
    float nrm = 0.f;
    #pragma unroll
    for (int f = 0; f < DK; ++f) nrm = fmaf(acc[f], acc[f], nrm);
    float inv = 1.f / fmaxf(sqrtf(nrm), 1e-12f);
    #pragma unroll
    for (int f = 0; f < DK; ++f) acc[f] *= inv;
    #pragma unroll
    for (int f = 0; f < DK; ++f) Pr[f] = acc[f];

    // last iteration: dense output half-row
    if (A.outp) {
        float* dst = A.outp + (size_t)gnode * DD + k * DK;
        #pragma unroll
        for (int f = 0; f < DK; ++f) dst[f] = acc[f];
    }

    // scores from registers. at[e] flat [2][50]: row-side at e*100+k*50+f,
    // col-side at e*100+k*50+25+f.
    const float* at = A.at;
    if (is0) {
        float s = 0.f, sc = 0.f;
        #pragma unroll
        for (int f = 0; f < DK; ++f) {
            s  = fmaf(acc[f], at[k * 50 + f], s);
            sc = fmaf(acc[f], at[100 + k * 50 + 25 + f], sc);
        }
        A.sa[0][2 * node + k] = s;
        A.sb1[2 * node + k]   = sc;
    } else {
        #pragma unroll 1
        for (int e = 1; e < 8; ++e) {
            const float* ap = at + e * 100 + k * 50;
            float s = 0.f;
            #pragma unroll
            for (int f = 0; f < DK; ++f) s = fmaf(acc[f], ap[f], s);
            A.sa[e][2 * node + k] = s;
        }
        float sc = 0.f;
        #pragma unroll
        for (int f = 0; f < DK; ++f) sc = fmaf(acc[f], at[k * 50 + 25 + f], sc);
        A.sb0[2 * node + k] = sc;
    }
}

static inline int cdiv(int a, int b) { return (a + b - 1) / b; }

extern "C" void kernel_launch(void* const* d_in, const int* in_sizes, int n_in,
                              void* d_out, int out_size, void* d_ws, size_t ws_size,
                              hipStream_t stream) {
    const int* edge[8];
    int E[8];
    for (int e = 0; e < 8; ++e) { edge[e] = (const int*)d_in[e]; E[e] = in_sizes[e] / 2; }
    const float* emb[8];
    int nn[8];
    for (int i = 0; i < 8; ++i) { emb[i] = (const float*)d_in[8 + i]; nn[i] = in_sizes[8 + i] / DD; }
    const float* Wtk = (const float*)d_in[16];
    const float* at  = (const float*)d_in[17];
    const float* W   = (const float*)d_in[18];
    const float* q   = (const float*)d_in[19];
    float* out = (float*)d_out;

    static const int aIdx[8] = {0, 1, 1, 1, 1, 1, 1, 1};
    static const int bIdx[8] = {1, 0, 2, 3, 4, 5, 6, 7};
    int rows[8], ncol[8];
    for (int e = 0; e < 8; ++e) { rows[e] = nn[aIdx[e]]; ncol[e] = nn[bIdx[e]]; }
    int rowbase[9];
    rowbase[0] = 0;
    for (int e = 0; e < 8; ++e) rowbase[e + 1] = rowbase[e] + rows[e];
    int totalRows = rowbase[8];
    int ebase[9];
    ebase[0] = 0;
    for (int e = 0; e < 8; ++e) ebase[e + 1] = ebase[e] + E[e];
    int totE = ebase[8];

    // ---- workspace: P(52), z(52), sb, sa, cnt, bsum, colind(u16) ----
    char* w = (char*)d_ws;
    size_t off = 0;
    auto alloc_f  = [&](size_t n) { float*  p = (float*)(w + off);  off += n * 4; return p; };
    auto alloc_f2 = [&](size_t n) { float2* p = (float2*)(w + off); off += n * 8; return p; };
    auto alloc_i  = [&](size_t n) { int*    p = (int*)(w + off);    off += n * 4; return p; };
    float* P[8]; for (int i = 0; i < 8; ++i) P[i] = alloc_f((size_t)nn[i] * PS);
    float* z[8]; for (int e = 0; e < 8; ++e) z[e] = alloc_f((size_t)rows[e] * PS);
    float2* sb[8]; for (int e = 0; e < 8; ++e) sb[e] = alloc_f2((size_t)ncol[e]);
    float2* sa[8]; for (int e = 0; e < 8; ++e) sa[e] = alloc_f2((size_t)rows[e]);
    int* cnt = alloc_i((size_t)totalRows);
    int nchunks = cdiv(totalRows, 1024);
    int* bsum = alloc_i((size_t)nchunks);
    unsigned short* colind = (unsigned short*)(w + off);
    off += (size_t)totE * 2;
    (void)ws_size;

    const int B = 256;

    // ---- flat CSR build ----
    hipMemsetAsync(cnt, 0, (size_t)totalRows * 4, stream);
    EdgeArgs EA;
    for (int e = 0; e < 8; ++e) {
        EA.rows[e] = edge[e]; EA.cols[e] = edge[e] + E[e];
        EA.rowbase[e] = rowbase[e];
        EA.ebase[e] = ebase[e];
    }
    EA.ebase[8] = ebase[8];
    EA.cnt = cnt; EA.colind = colind;
    hist_kernel<<<cdiv(totE, B), B, 0, stream>>>(EA);
    scan_part_kernel<<<nchunks, 1024, 0, stream>>>(cnt, totalRows, bsum);
    scan_bsum_kernel<<<1, 1024, 0, stream>>>(bsum, nchunks);
    add_off_kernel<<<nchunks, 1024, 0, stream>>>(cnt, totalRows, bsum);
    scatter_kernel<<<cdiv(totE, B), B, 0, stream>>>(EA);   // leaves cnt[w] = inclusive end

    // ---- fac ----
    FacArgs FA;
    FA.base[0] = 0;
    for (int i = 0; i < 8; ++i) { FA.emb[i] = emb[i]; FA.P[i] = P[i]; FA.base[i + 1] = FA.base[i] + nn[i]; }
    FA.Wtk = Wtk;
    fac_kernel<<<cdiv(FA.base[8], B), B, 0, stream>>>(FA);

    // ---- static sb (rels 2..7) once ----
    SbArgs SBs;
    SBs.base[0] = 0;
    for (int e = 2; e < 8; ++e) {
        SBs.Pb[e - 2] = P[bIdx[e]];
        SBs.at[e - 2] = at + (size_t)e * KF * DD;
        SBs.sb[e - 2] = sb[e];
        SBs.base[e - 1] = SBs.base[e - 2] + ncol[e];
    }
    sb_kernel<<<cdiv(SBs.base[6], B), B, 0, stream>>>(SBs);

    // ---- initial dynamic scores (sa all rels + sb0/sb1) ----
    ScoreArgs SC;
    SC.P0 = P[0]; SC.P1 = P[1]; SC.at = at;
    for (int e = 0; e < 8; ++e) SC.sa[e] = sa[e];
    SC.sb0 = sb[0]; SC.sb1 = sb[1];
    SC.n0 = nn[0]; SC.n1 = nn[1];
    score01_kernel<<<cdiv(nn[0] + nn[1], B), B, 0, stream>>>(SC);

    // ---- iterations ----
    PhaseArgs PA;
    PA.rowptr = cnt; PA.colind = colind;
    for (int e = 0; e < 8; ++e) {
        PA.Pb[e] = P[bIdx[e]];
        PA.sa[e] = sa[e]; PA.sb[e] = sb[e];
        PA.z[e] = z[e];
        PA.rowbase[e] = rowbase[e];
    }
    PA.rowbase[8] = rowbase[8];

    Ego3Args G3;
    G3.P0 = P[0]; G3.P1 = P[1]; G3.n0 = nn[0]; G3.n1 = nn[1];
    for (int e = 0; e < 8; ++e) { G3.zz[e] = z[e]; G3.sa[e] = (float*)sa[e]; }
    G3.W = W; G3.q = q; G3.at = at;
    G3.sb0 = (float*)sb[0]; G3.sb1 = (float*)sb[1];
    G3.outp = nullptr;

    int egoThreads = 2 * (nn[0] + nn[1]);
    for (int it = 0; it < ITERS; ++it) {
        phase_kernel<<<cdiv(totalRows, WPB), WPB * 64, 0, stream>>>(PA, totalRows);
        G3.outp = (it == ITERS - 1) ? out : nullptr;
        ego3_kernel<<<cdiv(egoThreads, B), B, 0, stream>>>(G3);
    }
}

// Round 7
// 1647.112 us; speedup vs baseline: 1.5854x; 1.5854x over previous
//
#include <hip/hip_runtime.h>
#include <math.h>

// GraphEncoder v14 = v7 (proven 1749us) with only verified-good deltas.
// Seven-round synthesis:
//  - per-thread W-matvec (ego3/ego2) spills structurally (3 attempts, all
//    VGPR=256 + 400MB scratch): th needs all 25 ov[f], each ov[f] needs 25
//    LDS reads -> scheduler keeps ~100 values live. Matvec stays WAVE-parallel
//    (one lane per output element, scalar o) inside the fat phase.
//  - lean phase = 215us vs fat 276us => in-wave epilogue costs ~61us; cut it
//    via LDS broadcast matvec (v12 epilogue, verified) instead of the 25-deep
//    serial shfl chain.
//  - sub4<13 mask: FETCH 306->277MB (v12, no-swizzle datum). Keep.
//  - XCD swizzle (v11: imbalance, -36us) and shuffle-free gather (v12:
//    16x redundant exp, VALU 54%) both reverted.
//  - z rows at PS stride + float4 ego loads + out-copy fused into last ego.

#define KF 2
#define DK 25
#define DD 50
#define PS 52   // padded P/z row stride: 208 B = 13 float4
#define ITERS 4
#define WPB 4

static __device__ __forceinline__ float leakyf(float x) { return x > 0.f ? x : 0.2f * x; }

// tanh via exp: rel err ~1e-6, monotone, saturates correctly.
static __device__ __forceinline__ float fast_tanhf(float x) {
    float e = __expf(2.f * x);
    return 1.f - 2.f * __builtin_amdgcn_rcpf(e + 1.f);
}

// at[e] is [2][50]: factor k at a+k*50; 0..24 row-side, 25..49 col-side.
static __device__ __forceinline__ float2 score_row50(const float* p, const float* a) {
    float s0 = 0.f, s1 = 0.f;
    #pragma unroll
    for (int f = 0; f < DK; ++f) {
        s0 = fmaf(p[f],      a[f],      s0);
        s1 = fmaf(p[DK + f], a[50 + f], s1);
    }
    return make_float2(s0, s1);
}
static __device__ __forceinline__ float2 score_col50(const float* p, const float* a) {
    float s0 = 0.f, s1 = 0.f;
    #pragma unroll
    for (int f = 0; f < DK; ++f) {
        s0 = fmaf(p[f],      a[25 + f], s0);
        s1 = fmaf(p[DK + f], a[75 + f], s1);
    }
    return make_float2(s0, s1);
}

// ---------------- fac ----------------
struct FacArgs { const float* emb[8]; float* P[8]; const float* Wtk; int base[9]; };

__global__ void fac_kernel(FacArgs A) {
    int g = blockIdx.x * blockDim.x + threadIdx.x;
    if (g >= A.base[8]) return;
    int ty = 0;
    while (g >= A.base[ty + 1]) ++ty;
    int node = g - A.base[ty];
    const float* er = A.emb[ty] + (size_t)node * DD;
    const float* Wt = A.Wtk + (size_t)ty * KF * DD * DK;
    float x[DD];
    #pragma unroll
    for (int d = 0; d < DD; ++d) x[d] = er[d];
    float out[DD];
    #pragma unroll
    for (int k = 0; k < KF; ++k) {
        const float* Wk = Wt + k * DD * DK;
        float nrm = 0.f;
        for (int f = 0; f < DK; ++f) {
            float acc = 0.f;
            for (int d = 0; d < DD; ++d) acc = fmaf(x[d], Wk[d * DK + f], acc);
            acc = leakyf(acc);
            out[k * DK + f] = acc;
            nrm = fmaf(acc, acc, nrm);
        }
        float inv = 1.f / fmaxf(sqrtf(nrm), 1e-12f);
        for (int f = 0; f < DK; ++f) out[k * DK + f] *= inv;
    }
    float* Pr = A.P[ty] + (size_t)node * PS;
    #pragma unroll
    for (int j = 0; j < DD; ++j) Pr[j] = out[j];
    Pr[50] = 0.f; Pr[51] = 0.f;
}

// ---------------- flat CSR build ----------------
struct EdgeArgs {
    const int* rows[8]; const int* cols[8];
    int* cnt;                  // [totalRows] global-row counts -> rowptr
    unsigned short* colind;    // [totE] flat
    int ebase[9];
    int rowbase[8];
};

__global__ void hist_kernel(EdgeArgs A) {
    int g = blockIdx.x * blockDim.x + threadIdx.x;
    if (g >= A.ebase[8]) return;
    int rel = 0;
    while (g >= A.ebase[rel + 1]) ++rel;
    int e = g - A.ebase[rel];
    atomicAdd(&A.cnt[A.rowbase[rel] + A.rows[rel][e]], 1);
}

// 3-kernel hierarchical exclusive scan over cnt[0..n)
__global__ __launch_bounds__(1024) void scan_part_kernel(int* a, int n, int* bsum) {
    __shared__ int lds[1024];
    int tid = threadIdx.x;
    int i = blockIdx.x * 1024 + tid;
    int v = (i < n) ? a[i] : 0;
    lds[tid] = v;
    __syncthreads();
    int x = v;
    for (int off = 1; off < 1024; off <<= 1) {
        int y = (tid >= off) ? lds[tid - off] : 0;
        __syncthreads();
        x += y;
        lds[tid] = x;
        __syncthreads();
    }
    if (i < n) a[i] = x - v;              // exclusive within chunk
    if (tid == 1023) bsum[blockIdx.x] = x; // chunk total
}

__global__ __launch_bounds__(1024) void scan_bsum_kernel(int* bsum, int nb) {
    __shared__ int lds[1024];
    int tid = threadIdx.x;
    int v = (tid < nb) ? bsum[tid] : 0;
    lds[tid] = v;
    __syncthreads();
    int x = v;
    for (int off = 1; off < 1024; off <<= 1) {
        int y = (tid >= off) ? lds[tid - off] : 0;
        __syncthreads();
        x += y;
        lds[tid] = x;
        __syncthreads();
    }
    if (tid < nb) bsum[tid] = x - v;      // exclusive chunk offsets
}

__global__ __launch_bounds__(1024) void add_off_kernel(int* a, int n, const int* bsum) {
    int i = blockIdx.x * 1024 + threadIdx.x;
    if (i < n) a[i] += bsum[blockIdx.x];
}

// scatter bumps cnt in place; afterwards cnt[w] == inclusive end of global row w.
__global__ void scatter_kernel(EdgeArgs A) {
    int g = blockIdx.x * blockDim.x + threadIdx.x;
    if (g >= A.ebase[8]) return;
    int rel = 0;
    while (g >= A.ebase[rel + 1]) ++rel;
    int e = g - A.ebase[rel];
    int p = atomicAdd(&A.cnt[A.rowbase[rel] + A.rows[rel][e]], 1);
    A.colind[p] = (unsigned short)A.cols[rel][e];
}

// ---------------- sb init for static relations 2..7 ----------------
struct SbArgs { const float* Pb[6]; const float* at[6]; float2* sb[6]; int base[7]; };

__global__ void sb_kernel(SbArgs A) {
    int g = blockIdx.x * blockDim.x + threadIdx.x;
    if (g >= A.base[6]) return;
    int rel = 0;
    while (g >= A.base[rel + 1]) ++rel;
    int c = g - A.base[rel];
    const float* p = A.Pb[rel] + (size_t)c * PS;
    A.sb[rel][c] = score_col50(p, A.at[rel]);
}

// ---------------- score01: per-iteration sa (all rels) + sb0/sb1 ----------------
struct ScoreArgs {
    const float* P0; const float* P1;
    const float* at;
    float2* sa[8]; float2* sb0; float2* sb1;
    int n0, n1;
};

__global__ void score01_kernel(ScoreArgs A) {
    int g = blockIdx.x * blockDim.x + threadIdx.x;
    if (g >= A.n0 + A.n1) return;
    if (g < A.n0) {
        const float* p = A.P0 + (size_t)g * PS;
        float pr[DD];
        #pragma unroll
        for (int j = 0; j < DD; ++j) pr[j] = p[j];
        A.sa[0][g] = score_row50(pr, A.at + 0);
        A.sb1[g]   = score_col50(pr, A.at + 100);
    } else {
        int node = g - A.n0;
        const float* p = A.P1 + (size_t)node * PS;
        float pr[DD];
        #pragma unroll
        for (int j = 0; j < DD; ++j) pr[j] = p[j];
        #pragma unroll
        for (int e = 1; e < 8; ++e) A.sa[e][node] = score_row50(pr, A.at + e * 100);
        A.sb0[node] = score_col50(pr, A.at + 0);
    }
}

// ---------------- fused phase (v7 gather + masked loads + LDS epilogue) ----------------
struct PhaseArgs {
    const int* rowptr;               // [totalRows] inclusive ends (flat)
    const unsigned short* colind;    // flat
    const float* Pb[8];
    const float* q[8];
    const float2* sa[8]; const float2* sb[8];
    float* z[8]; float* r[8];
    const float* W;
    int rowbase[9];
};

__global__ __launch_bounds__(WPB * 64) void phase_kernel(PhaseArgs A, int totalRows) {
    __shared__ float Wsh[DK * DK];
    __shared__ float zsh[WPB][DD];
    for (int i = threadIdx.x; i < DK * DK; i += WPB * 64) Wsh[i] = A.W[i];
    __syncthreads();

    int wslot = threadIdx.x >> 6;
    int wave = blockIdx.x * WPB + wslot;
    int lane = threadIdx.x & 63;
    if (wave >= totalRows) return;
    int rel = 0;
    while (wave >= A.rowbase[rel + 1]) ++rel;
    int u = wave - A.rowbase[rel];

    const unsigned short* colind = A.colind;
    const float* Pb = A.Pb[rel];
    const float* qv = A.q[rel];
    const float2* sb = A.sb[rel];
    float2 h = A.sa[rel][u];
    int beg = wave ? A.rowptr[wave - 1] : 0;
    int end = A.rowptr[wave];

    bool act = lane < DD;
    int grp4 = lane >> 4, sub4 = lane & 15;
    bool ld = sub4 < 13;   // P row is 13 float4; 16 would touch a 5th line
    float ssum = 0.f;
    float4 a4 = make_float4(0.f, 0.f, 0.f, 0.f);

    for (int base = beg; base < end; base += 64) {
        int idx = base + lane;
        bool vld = idx < end;
        int cb = vld ? (int)colind[idx] : 0;
        float evl = 0.f;
        if (vld) {
            float2 sc = sb[cb];
            evl = __expf(0.5f * (fmaxf(h.x + sc.x, 0.f) + fmaxf(h.y + sc.y, 0.f)));
        }
        ssum += evl;
        int nb = min(64, end - base);
        #pragma unroll 2
        for (int t = 0; t < nb; t += 4) {
            int srcl = t + grp4;
            int c = __shfl(cb, srcl);
            float ev = __shfl(evl, srcl);
            if (ld) {
                const float4* pc = (const float4*)(Pb + (size_t)c * PS);
                float4 v = pc[sub4];
                a4.x = fmaf(ev, v.x, a4.x);
                a4.y = fmaf(ev, v.y, a4.y);
                a4.z = fmaf(ev, v.z, a4.z);
                a4.w = fmaf(ev, v.w, a4.w);
            }
        }
    }
    #pragma unroll
    for (int off = 32; off >= 16; off >>= 1) {
        a4.x += __shfl_xor(a4.x, off);
        a4.y += __shfl_xor(a4.y, off);
        a4.z += __shfl_xor(a4.z, off);
        a4.w += __shfl_xor(a4.w, off);
    }
    #pragma unroll
    for (int off = 32; off; off >>= 1) ssum += __shfl_xor(ssum, off);

    int src = lane >> 2;
    float fx = __shfl(a4.x, src), fy = __shfl(a4.y, src);
    float fz = __shfl(a4.z, src), fw = __shfl(a4.w, src);
    float za = (lane & 1) ? ((lane & 2) ? fw : fy) : ((lane & 2) ? fz : fx);

    float inv = (ssum > 0.f) ? (1.f / ssum) : 0.f;
    float zl = act ? leakyf(za * inv) : 0.f;

    // epilogue matvec via LDS broadcast reads (25 pipelined ds_reads per lane
    // instead of a 25-deep serial shfl chain; scalar o per lane, no arrays)
    if (act) zsh[wslot][lane] = zl;
    int fcol = act ? ((lane < DK) ? lane : (lane - DK)) : 0;
    int kbase = (act && lane >= DK) ? DK : 0;
    float o = 0.f;
    #pragma unroll
    for (int d = 0; d < DK; ++d)
        o = fmaf(zsh[wslot][kbase + d], Wsh[d * DK + fcol], o);

    float th = act ? fast_tanhf(o) * qv[fcol] : 0.f;
    float t0 = (lane < DK) ? th : 0.f;
    float t1 = th - t0;
    #pragma unroll
    for (int off = 32; off; off >>= 1) { t0 += __shfl_xor(t0, off); t1 += __shfl_xor(t1, off); }
    float m = fmaxf(t0, t1);
    float e0 = __expf(t0 - m), e1 = __expf(t1 - m);
    float rinv = 1.f / (e0 + e1);

    if (act) A.z[rel][(size_t)u * PS + lane] = o;
    if (lane == 0) {
        A.r[rel][(size_t)u * 2 + 0] = e0 * rinv;
        A.r[rel][(size_t)u * 2 + 1] = e1 * rinv;
    }
}

// ---------------- ego (float4 z loads + fused out) ----------------
struct EgoArgs {
    float* P0; float* P1;
    const float* zz[8];   // PS stride
    const float* rr[8];
    float* outp;          // non-null on last iteration
    int n0, n1;
};

__global__ void ego_kernel(EgoArgs A) {
    int g = blockIdx.x * blockDim.x + threadIdx.x;
    if (g >= A.n0 + A.n1) return;
    float acc[DD];
    bool is0 = g < A.n0;
    int node = is0 ? g : g - A.n0;
    float* Pr = (is0 ? A.P0 : A.P1) + (size_t)node * PS;
    {
        const float4* p4 = (const float4*)Pr;
        #pragma unroll
        for (int t = 0; t < 12; ++t) {
            float4 v = p4[t];
            acc[4 * t] = v.x; acc[4 * t + 1] = v.y; acc[4 * t + 2] = v.z; acc[4 * t + 3] = v.w;
        }
        acc[48] = Pr[48]; acc[49] = Pr[49];
    }
    int jbeg = is0 ? 0 : 1, jend = is0 ? 1 : 8;
    for (int j = jbeg; j < jend; ++j) {
        const float* zr = A.zz[j] + (size_t)node * PS;
        float r0 = A.rr[j][(size_t)node * 2], r1 = A.rr[j][(size_t)node * 2 + 1];
        const float4* z4 = (const float4*)zr;
        #pragma unroll
        for (int t = 0; t < 12; ++t) {
            float4 v = z4[t];
            acc[4 * t]     = fmaf(v.x, (4 * t     < DK) ? r0 : r1, acc[4 * t]);
            acc[4 * t + 1] = fmaf(v.y, (4 * t + 1 < DK) ? r0 : r1, acc[4 * t + 1]);
            acc[4 * t + 2] = fmaf(v.z, (4 * t + 2 < DK) ? r0 : r1, acc[4 * t + 2]);
            acc[4 * t + 3] = fmaf(v.w, (4 * t + 3 < DK) ? r0 : r1, acc[4 * t + 3]);
        }
        acc[48] = fmaf(zr[48], r1, acc[48]);
        acc[49] = fmaf(zr[49], r1, acc[49]);
    }
    // l2norm per factor, store
    #pragma unroll
    for (int k = 0; k < KF; ++k) {
        float nrm = 0.f;
        #pragma unroll
        for (int f = 0; f < DK; ++f) nrm = fmaf(acc[k * DK + f], acc[k * DK + f], nrm);
        float inv = 1.f / fmaxf(sqrtf(nrm), 1e-12f);
        #pragma unroll
        for (int f = 0; f < DK; ++f) acc[k * DK + f] *= inv;
    }
    #pragma unroll
    for (int f = 0; f < DD; ++f) Pr[f] = acc[f];
    if (A.outp) {
        float* dst = A.outp + (size_t)g * DD;
        #pragma unroll
        for (int f = 0; f < DD; ++f) dst[f] = acc[f];
    }
}

static inline int cdiv(int a, int b) { return (a + b - 1) / b; }

extern "C" void kernel_launch(void* const* d_in, const int* in_sizes, int n_in,
                              void* d_out, int out_size, void* d_ws, size_t ws_size,
                              hipStream_t stream) {
    const int* edge[8];
    int E[8];
    for (int e = 0; e < 8; ++e) { edge[e] = (const int*)d_in[e]; E[e] = in_sizes[e] / 2; }
    const float* emb[8];
    int nn[8];
    for (int i = 0; i < 8; ++i) { emb[i] = (const float*)d_in[8 + i]; nn[i] = in_sizes[8 + i] / DD; }
    const float* Wtk = (const float*)d_in[16];
    const float* at  = (const float*)d_in[17];
    const float* W   = (const float*)d_in[18];
    const float* q   = (const float*)d_in[19];
    float* out = (float*)d_out;

    static const int aIdx[8] = {0, 1, 1, 1, 1, 1, 1, 1};
    static const int bIdx[8] = {1, 0, 2, 3, 4, 5, 6, 7};
    int rows[8], ncol[8];
    for (int e = 0; e < 8; ++e) { rows[e] = nn[aIdx[e]]; ncol[e] = nn[bIdx[e]]; }
    int rowbase[9];
    rowbase[0] = 0;
    for (int e = 0; e < 8; ++e) rowbase[e + 1] = rowbase[e] + rows[e];
    int totalRows = rowbase[8];
    int ebase[9];
    ebase[0] = 0;
    for (int e = 0; e < 8; ++e) ebase[e + 1] = ebase[e] + E[e];
    int totE = ebase[8];

    // ---- workspace: P(52), z(52), r, sb, sa, cnt, bsum, colind(u16) ----
    char* w = (char*)d_ws;
    size_t off = 0;
    auto alloc_f  = [&](size_t n) { float*  p = (float*)(w + off);  off += n * 4; return p; };
    auto alloc_f2 = [&](size_t n) { float2* p = (float2*)(w + off); off += n * 8; return p; };
    auto alloc_i  = [&](size_t n) { int*    p = (int*)(w + off);    off += n * 4; return p; };
    float* P[8]; for (int i = 0; i < 8; ++i) P[i] = alloc_f((size_t)nn[i] * PS);
    float* z[8]; for (int e = 0; e < 8; ++e) z[e] = alloc_f((size_t)rows[e] * PS);
    float* r[8]; for (int e = 0; e < 8; ++e) r[e] = alloc_f((size_t)rows[e] * 2);
    float2* sb[8]; for (int e = 0; e < 8; ++e) sb[e] = alloc_f2((size_t)ncol[e]);
    float2* sa[8]; for (int e = 0; e < 8; ++e) sa[e] = alloc_f2((size_t)rows[e]);
    int* cnt = alloc_i((size_t)totalRows);
    int nchunks = cdiv(totalRows, 1024);
    int* bsum = alloc_i((size_t)nchunks);
    unsigned short* colind = (unsigned short*)(w + off);
    off += (size_t)totE * 2;
    (void)ws_size;

    const int B = 256;

    // ---- flat CSR build ----
    hipMemsetAsync(cnt, 0, (size_t)totalRows * 4, stream);
    EdgeArgs EA;
    for (int e = 0; e < 8; ++e) {
        EA.rows[e] = edge[e]; EA.cols[e] = edge[e] + E[e];
        EA.rowbase[e] = rowbase[e];
        EA.ebase[e] = ebase[e];
    }
    EA.ebase[8] = ebase[8];
    EA.cnt = cnt; EA.colind = colind;
    hist_kernel<<<cdiv(totE, B), B, 0, stream>>>(EA);
    scan_part_kernel<<<nchunks, 1024, 0, stream>>>(cnt, totalRows, bsum);
    scan_bsum_kernel<<<1, 1024, 0, stream>>>(bsum, nchunks);
    add_off_kernel<<<nchunks, 1024, 0, stream>>>(cnt, totalRows, bsum);
    scatter_kernel<<<cdiv(totE, B), B, 0, stream>>>(EA);   // leaves cnt[w] = inclusive end

    // ---- fac ----
    FacArgs FA;
    FA.base[0] = 0;
    for (int i = 0; i < 8; ++i) { FA.emb[i] = emb[i]; FA.P[i] = P[i]; FA.base[i + 1] = FA.base[i] + nn[i]; }
    FA.Wtk = Wtk;
    fac_kernel<<<cdiv(FA.base[8], B), B, 0, stream>>>(FA);

    // ---- static sb (rels 2..7) once ----
    SbArgs SBs;
    SBs.base[0] = 0;
    for (int e = 2; e < 8; ++e) {
        SBs.Pb[e - 2] = P[bIdx[e]];
        SBs.at[e - 2] = at + (size_t)e * KF * DD;
        SBs.sb[e - 2] = sb[e];
        SBs.base[e - 1] = SBs.base[e - 2] + ncol[e];
    }
    sb_kernel<<<cdiv(SBs.base[6], B), B, 0, stream>>>(SBs);

    // ---- dynamic scores (sa all rels + sb0/sb1) ----
    ScoreArgs SC;
    SC.P0 = P[0]; SC.P1 = P[1]; SC.at = at;
    for (int e = 0; e < 8; ++e) SC.sa[e] = sa[e];
    SC.sb0 = sb[0]; SC.sb1 = sb[1];
    SC.n0 = nn[0]; SC.n1 = nn[1];
    score01_kernel<<<cdiv(nn[0] + nn[1], B), B, 0, stream>>>(SC);

    // ---- iterations ----
    PhaseArgs PA;
    PA.rowptr = cnt; PA.colind = colind;
    for (int e = 0; e < 8; ++e) {
        PA.Pb[e] = P[bIdx[e]];
        PA.q[e]  = q + (size_t)e * DK;
        PA.sa[e] = sa[e]; PA.sb[e] = sb[e];
        PA.z[e] = z[e]; PA.r[e] = r[e];
        PA.rowbase[e] = rowbase[e];
    }
    PA.rowbase[8] = rowbase[8];
    PA.W = W;
    EgoArgs GA;
    GA.P0 = P[0]; GA.P1 = P[1]; GA.n0 = nn[0]; GA.n1 = nn[1];
    for (int e = 0; e < 8; ++e) { GA.zz[e] = z[e]; GA.rr[e] = r[e]; }
    GA.outp = nullptr;

    for (int it = 0; it < ITERS; ++it) {
        phase_kernel<<<cdiv(totalRows, WPB), WPB * 64, 0, stream>>>(PA, totalRows);
        GA.outp = (it == ITERS - 1) ? out : nullptr;
        ego_kernel<<<cdiv(nn[0] + nn[1], B), B, 0, stream>>>(GA);
        if (it != ITERS - 1)
            score01_kernel<<<cdiv(nn[0] + nn[1], B), B, 0, stream>>>(SC);
    }
}

// Round 8
// 1614.978 us; speedup vs baseline: 1.6170x; 1.0199x over previous
//
#include <hip/hip_runtime.h>
#include <math.h>

// GraphEncoder v15 = v14 (1647us, best) + two levers:
//  (1) phase t-loop: shuffle precomputed BYTE OFFSETS (kills per-t-iter
//      c*208 mul + 64-bit extend) and unroll 4 (VGPR 20 -> ~45, 4 gathers
//      in flight instead of 2).
//  (2) ego: fuse the per-iteration score01 (scores ONLY - the W-matvec stays
//      wave-parallel in phase; matvec was the v8-v10 spiller, scores never
//      isolated-tested). acc[50] is the new P row in registers; computing
//      sa/sb there removes 3 launches + 3x19MB P re-reads. __launch_bounds__
//      (256) lifts the default 128-VGPR cap; unroll 1 on the e-loop.
// Verified-kept: sub4<13 mask, LDS-broadcast epilogue matvec, z at PS
// stride, float4 ego, fused out-copy. Rejected by data: XCD swizzle (v11),
// shuffle-free gather (v12), per-thread matvec (v8/v9/v10/v13).

#define KF 2
#define DK 25
#define DD 50
#define PS 52   // padded P/z row stride: 208 B = 13 float4
#define ITERS 4
#define WPB 4

static __device__ __forceinline__ float leakyf(float x) { return x > 0.f ? x : 0.2f * x; }

// tanh via exp: rel err ~1e-6, monotone, saturates correctly.
static __device__ __forceinline__ float fast_tanhf(float x) {
    float e = __expf(2.f * x);
    return 1.f - 2.f * __builtin_amdgcn_rcpf(e + 1.f);
}

// at[e] is [2][50]: factor k at a+k*50; 0..24 row-side, 25..49 col-side.
static __device__ __forceinline__ float2 score_row50(const float* p, const float* a) {
    float s0 = 0.f, s1 = 0.f;
    #pragma unroll
    for (int f = 0; f < DK; ++f) {
        s0 = fmaf(p[f],      a[f],      s0);
        s1 = fmaf(p[DK + f], a[50 + f], s1);
    }
    return make_float2(s0, s1);
}
static __device__ __forceinline__ float2 score_col50(const float* p, const float* a) {
    float s0 = 0.f, s1 = 0.f;
    #pragma unroll
    for (int f = 0; f < DK; ++f) {
        s0 = fmaf(p[f],      a[25 + f], s0);
        s1 = fmaf(p[DK + f], a[75 + f], s1);
    }
    return make_float2(s0, s1);
}

// ---------------- fac ----------------
struct FacArgs { const float* emb[8]; float* P[8]; const float* Wtk; int base[9]; };

__global__ void fac_kernel(FacArgs A) {
    int g = blockIdx.x * blockDim.x + threadIdx.x;
    if (g >= A.base[8]) return;
    int ty = 0;
    while (g >= A.base[ty + 1]) ++ty;
    int node = g - A.base[ty];
    const float* er = A.emb[ty] + (size_t)node * DD;
    const float* Wt = A.Wtk + (size_t)ty * KF * DD * DK;
    float x[DD];
    #pragma unroll
    for (int d = 0; d < DD; ++d) x[d] = er[d];
    float out[DD];
    #pragma unroll
    for (int k = 0; k < KF; ++k) {
        const float* Wk = Wt + k * DD * DK;
        float nrm = 0.f;
        for (int f = 0; f < DK; ++f) {
            float acc = 0.f;
            for (int d = 0; d < DD; ++d) acc = fmaf(x[d], Wk[d * DK + f], acc);
            acc = leakyf(acc);
            out[k * DK + f] = acc;
            nrm = fmaf(acc, acc, nrm);
        }
        float inv = 1.f / fmaxf(sqrtf(nrm), 1e-12f);
        for (int f = 0; f < DK; ++f) out[k * DK + f] *= inv;
    }
    float* Pr = A.P[ty] + (size_t)node * PS;
    #pragma unroll
    for (int j = 0; j < DD; ++j) Pr[j] = out[j];
    Pr[50] = 0.f; Pr[51] = 0.f;
}

// ---------------- flat CSR build ----------------
struct EdgeArgs {
    const int* rows[8]; const int* cols[8];
    int* cnt;                  // [totalRows] global-row counts -> rowptr
    unsigned short* colind;    // [totE] flat
    int ebase[9];
    int rowbase[8];
};

__global__ void hist_kernel(EdgeArgs A) {
    int g = blockIdx.x * blockDim.x + threadIdx.x;
    if (g >= A.ebase[8]) return;
    int rel = 0;
    while (g >= A.ebase[rel + 1]) ++rel;
    int e = g - A.ebase[rel];
    atomicAdd(&A.cnt[A.rowbase[rel] + A.rows[rel][e]], 1);
}

// 3-kernel hierarchical exclusive scan over cnt[0..n)
__global__ __launch_bounds__(1024) void scan_part_kernel(int* a, int n, int* bsum) {
    __shared__ int lds[1024];
    int tid = threadIdx.x;
    int i = blockIdx.x * 1024 + tid;
    int v = (i < n) ? a[i] : 0;
    lds[tid] = v;
    __syncthreads();
    int x = v;
    for (int off = 1; off < 1024; off <<= 1) {
        int y = (tid >= off) ? lds[tid - off] : 0;
        __syncthreads();
        x += y;
        lds[tid] = x;
        __syncthreads();
    }
    if (i < n) a[i] = x - v;              // exclusive within chunk
    if (tid == 1023) bsum[blockIdx.x] = x; // chunk total
}

__global__ __launch_bounds__(1024) void scan_bsum_kernel(int* bsum, int nb) {
    __shared__ int lds[1024];
    int tid = threadIdx.x;
    int v = (tid < nb) ? bsum[tid] : 0;
    lds[tid] = v;
    __syncthreads();
    int x = v;
    for (int off = 1; off < 1024; off <<= 1) {
        int y = (tid >= off) ? lds[tid - off] : 0;
        __syncthreads();
        x += y;
        lds[tid] = x;
        __syncthreads();
    }
    if (tid < nb) bsum[tid] = x - v;      // exclusive chunk offsets
}

__global__ __launch_bounds__(1024) void add_off_kernel(int* a, int n, const int* bsum) {
    int i = blockIdx.x * 1024 + threadIdx.x;
    if (i < n) a[i] += bsum[blockIdx.x];
}

// scatter bumps cnt in place; afterwards cnt[w] == inclusive end of global row w.
__global__ void scatter_kernel(EdgeArgs A) {
    int g = blockIdx.x * blockDim.x + threadIdx.x;
    if (g >= A.ebase[8]) return;
    int rel = 0;
    while (g >= A.ebase[rel + 1]) ++rel;
    int e = g - A.ebase[rel];
    int p = atomicAdd(&A.cnt[A.rowbase[rel] + A.rows[rel][e]], 1);
    A.colind[p] = (unsigned short)A.cols[rel][e];
}

// ---------------- sb init for static relations 2..7 ----------------
struct SbArgs { const float* Pb[6]; const float* at[6]; float2* sb[6]; int base[7]; };

__global__ void sb_kernel(SbArgs A) {
    int g = blockIdx.x * blockDim.x + threadIdx.x;
    if (g >= A.base[6]) return;
    int rel = 0;
    while (g >= A.base[rel + 1]) ++rel;
    int c = g - A.base[rel];
    const float* p = A.Pb[rel] + (size_t)c * PS;
    A.sb[rel][c] = score_col50(p, A.at[rel]);
}

// ---------------- score01: INITIAL sa (all rels) + sb0/sb1 (after fac) ----------------
struct ScoreArgs {
    const float* P0; const float* P1;
    const float* at;
    float2* sa[8]; float2* sb0; float2* sb1;
    int n0, n1;
};

__global__ void score01_kernel(ScoreArgs A) {
    int g = blockIdx.x * blockDim.x + threadIdx.x;
    if (g >= A.n0 + A.n1) return;
    if (g < A.n0) {
        const float* p = A.P0 + (size_t)g * PS;
        float pr[DD];
        #pragma unroll
        for (int j = 0; j < DD; ++j) pr[j] = p[j];
        A.sa[0][g] = score_row50(pr, A.at + 0);
        A.sb1[g]   = score_col50(pr, A.at + 100);
    } else {
        int node = g - A.n0;
        const float* p = A.P1 + (size_t)node * PS;
        float pr[DD];
        #pragma unroll
        for (int j = 0; j < DD; ++j) pr[j] = p[j];
        #pragma unroll
        for (int e = 1; e < 8; ++e) A.sa[e][node] = score_row50(pr, A.at + e * 100);
        A.sb0[node] = score_col50(pr, A.at + 0);
    }
}

// ---------------- fused phase (gather + LDS epilogue; offset-shuffle, unroll 4) ----------------
struct PhaseArgs {
    const int* rowptr;               // [totalRows] inclusive ends (flat)
    const unsigned short* colind;    // flat
    const float* Pb[8];
    const float* q[8];
    const float2* sa[8]; const float2* sb[8];
    float* z[8]; float* r[8];
    const float* W;
    int rowbase[9];
};

__global__ __launch_bounds__(WPB * 64) void phase_kernel(PhaseArgs A, int totalRows) {
    __shared__ float Wsh[DK * DK];
    __shared__ float zsh[WPB][DD];
    for (int i = threadIdx.x; i < DK * DK; i += WPB * 64) Wsh[i] = A.W[i];
    __syncthreads();

    int wslot = threadIdx.x >> 6;
    int wave = blockIdx.x * WPB + wslot;
    int lane = threadIdx.x & 63;
    if (wave >= totalRows) return;
    int rel = 0;
    while (wave >= A.rowbase[rel + 1]) ++rel;
    int u = wave - A.rowbase[rel];

    const unsigned short* colind = A.colind;
    const char* Pb = (const char*)A.Pb[rel];
    const float* qv = A.q[rel];
    const float2* sb = A.sb[rel];
    float2 h = A.sa[rel][u];
    int beg = wave ? A.rowptr[wave - 1] : 0;
    int end = A.rowptr[wave];

    bool act = lane < DD;
    int grp4 = lane >> 4, sub4 = lane & 15;
    bool ld = sub4 < 13;   // P row is 13 float4; 16 would touch a 5th line
    float ssum = 0.f;
    float4 a4 = make_float4(0.f, 0.f, 0.f, 0.f);

    for (int base = beg; base < end; base += 64) {
        int idx = base + lane;
        bool vld = idx < end;
        int cb = vld ? (int)colind[idx] : 0;
        unsigned ob = (unsigned)cb * (unsigned)(PS * 4);   // byte offset, 64-wide
        float evl = 0.f;
        if (vld) {
            float2 sc = sb[cb];
            evl = __expf(0.5f * (fmaxf(h.x + sc.x, 0.f) + fmaxf(h.y + sc.y, 0.f)));
        }
        ssum += evl;
        int nb = min(64, end - base);
        #pragma unroll 4
        for (int t = 0; t < nb; t += 4) {
            int srcl = t + grp4;
            unsigned o4 = __shfl(ob, srcl);
            float ev = __shfl(evl, srcl);
            if (ld) {
                const float4* pc = (const float4*)(Pb + o4);
                float4 v = pc[sub4];
                a4.x = fmaf(ev, v.x, a4.x);
                a4.y = fmaf(ev, v.y, a4.y);
                a4.z = fmaf(ev, v.z, a4.z);
                a4.w = fmaf(ev, v.w, a4.w);
            }
        }
    }
    #pragma unroll
    for (int off = 32; off >= 16; off >>= 1) {
        a4.x += __shfl_xor(a4.x, off);
        a4.y += __shfl_xor(a4.y, off);
        a4.z += __shfl_xor(a4.z, off);
        a4.w += __shfl_xor(a4.w, off);
    }
    #pragma unroll
    for (int off = 32; off; off >>= 1) ssum += __shfl_xor(ssum, off);

    int src = lane >> 2;
    float fx = __shfl(a4.x, src), fy = __shfl(a4.y, src);
    float fz = __shfl(a4.z, src), fw = __shfl(a4.w, src);
    float za = (lane & 1) ? ((lane & 2) ? fw : fy) : ((lane & 2) ? fz : fx);

    float inv = (ssum > 0.f) ? (1.f / ssum) : 0.f;
    float zl = act ? leakyf(za * inv) : 0.f;

    // epilogue matvec via LDS broadcast reads (scalar o per lane, no arrays)
    if (act) zsh[wslot][lane] = zl;
    int fcol = act ? ((lane < DK) ? lane : (lane - DK)) : 0;
    int kbase = (act && lane >= DK) ? DK : 0;
    float o = 0.f;
    #pragma unroll
    for (int d = 0; d < DK; ++d)
        o = fmaf(zsh[wslot][kbase + d], Wsh[d * DK + fcol], o);

    float th = act ? fast_tanhf(o) * qv[fcol] : 0.f;
    float t0 = (lane < DK) ? th : 0.f;
    float t1 = th - t0;
    #pragma unroll
    for (int off = 32; off; off >>= 1) { t0 += __shfl_xor(t0, off); t1 += __shfl_xor(t1, off); }
    float m = fmaxf(t0, t1);
    float e0 = __expf(t0 - m), e1 = __expf(t1 - m);
    float rinv = 1.f / (e0 + e1);

    if (act) A.z[rel][(size_t)u * PS + lane] = o;
    if (lane == 0) {
        A.r[rel][(size_t)u * 2 + 0] = e0 * rinv;
        A.r[rel][(size_t)u * 2 + 1] = e1 * rinv;
    }
}

// ---------------- ego (float4 z loads + fused out + fused scores) ----------------
struct EgoArgs {
    float* P0; float* P1;
    const float* zz[8];   // PS stride
    const float* rr[8];
    const float* at;      // [8][2][50]
    float2* sa[8]; float2* sb0; float2* sb1;
    float* outp;          // non-null on last iteration (scores skipped then)
    int n0, n1;
};

__global__ __launch_bounds__(256) void ego_kernel(EgoArgs A) {
    int g = blockIdx.x * blockDim.x + threadIdx.x;
    if (g >= A.n0 + A.n1) return;
    float acc[DD];
    bool is0 = g < A.n0;
    int node = is0 ? g : g - A.n0;
    float* Pr = (is0 ? A.P0 : A.P1) + (size_t)node * PS;
    {
        const float4* p4 = (const float4*)Pr;
        #pragma unroll
        for (int t = 0; t < 12; ++t) {
            float4 v = p4[t];
            acc[4 * t] = v.x; acc[4 * t + 1] = v.y; acc[4 * t + 2] = v.z; acc[4 * t + 3] = v.w;
        }
        acc[48] = Pr[48]; acc[49] = Pr[49];
    }
    int jbeg = is0 ? 0 : 1, jend = is0 ? 1 : 8;
    #pragma unroll 1
    for (int j = jbeg; j < jend; ++j) {
        const float* zr = A.zz[j] + (size_t)node * PS;
        float r0 = A.rr[j][(size_t)node * 2], r1 = A.rr[j][(size_t)node * 2 + 1];
        const float4* z4 = (const float4*)zr;
        #pragma unroll
        for (int t = 0; t < 12; ++t) {
            float4 v = z4[t];
            acc[4 * t]     = fmaf(v.x, (4 * t     < DK) ? r0 : r1, acc[4 * t]);
            acc[4 * t + 1] = fmaf(v.y, (4 * t + 1 < DK) ? r0 : r1, acc[4 * t + 1]);
            acc[4 * t + 2] = fmaf(v.z, (4 * t + 2 < DK) ? r0 : r1, acc[4 * t + 2]);
            acc[4 * t + 3] = fmaf(v.w, (4 * t + 3 < DK) ? r0 : r1, acc[4 * t + 3]);
        }
        acc[48] = fmaf(zr[48], r1, acc[48]);
        acc[49] = fmaf(zr[49], r1, acc[49]);
    }
    // l2norm per factor, store
    #pragma unroll
    for (int k = 0; k < KF; ++k) {
        float nrm = 0.f;
        #pragma unroll
        for (int f = 0; f < DK; ++f) nrm = fmaf(acc[k * DK + f], acc[k * DK + f], nrm);
        float inv = 1.f / fmaxf(sqrtf(nrm), 1e-12f);
        #pragma unroll
        for (int f = 0; f < DK; ++f) acc[k * DK + f] *= inv;
    }
    #pragma unroll
    for (int f = 0; f < DD; ++f) Pr[f] = acc[f];

    if (A.outp) {
        // last iteration: dense output row; no further phase -> no scores
        float* dst = A.outp + (size_t)g * DD;
        #pragma unroll
        for (int f = 0; f < DD; ++f) dst[f] = acc[f];
        return;
    }

    // scores from the new P row (registers) — replaces in-loop score01
    if (is0) {
        A.sa[0][node] = score_row50(acc, A.at + 0);
        A.sb1[node]   = score_col50(acc, A.at + 100);
    } else {
        #pragma unroll 1
        for (int e = 1; e < 8; ++e) A.sa[e][node] = score_row50(acc, A.at + e * 100);
        A.sb0[node] = score_col50(acc, A.at + 0);
    }
}

static inline int cdiv(int a, int b) { return (a + b - 1) / b; }

extern "C" void kernel_launch(void* const* d_in, const int* in_sizes, int n_in,
                              void* d_out, int out_size, void* d_ws, size_t ws_size,
                              hipStream_t stream) {
    const int* edge[8];
    int E[8];
    for (int e = 0; e < 8; ++e) { edge[e] = (const int*)d_in[e]; E[e] = in_sizes[e] / 2; }
    const float* emb[8];
    int nn[8];
    for (int i = 0; i < 8; ++i) { emb[i] = (const float*)d_in[8 + i]; nn[i] = in_sizes[8 + i] / DD; }
    const float* Wtk = (const float*)d_in[16];
    const float* at  = (const float*)d_in[17];
    const float* W   = (const float*)d_in[18];
    const float* q   = (const float*)d_in[19];
    float* out = (float*)d_out;

    static const int aIdx[8] = {0, 1, 1, 1, 1, 1, 1, 1};
    static const int bIdx[8] = {1, 0, 2, 3, 4, 5, 6, 7};
    int rows[8], ncol[8];
    for (int e = 0; e < 8; ++e) { rows[e] = nn[aIdx[e]]; ncol[e] = nn[bIdx[e]]; }
    int rowbase[9];
    rowbase[0] = 0;
    for (int e = 0; e < 8; ++e) rowbase[e + 1] = rowbase[e] + rows[e];
    int totalRows = rowbase[8];
    int ebase[9];
    ebase[0] = 0;
    for (int e = 0; e < 8; ++e) ebase[e + 1] = ebase[e] + E[e];
    int totE = ebase[8];

    // ---- workspace: P(52), z(52), r, sb, sa, cnt, bsum, colind(u16) ----
    char* w = (char*)d_ws;
    size_t off = 0;
    auto alloc_f  = [&](size_t n) { float*  p = (float*)(w + off);  off += n * 4; return p; };
    auto alloc_f2 = [&](size_t n) { float2* p = (float2*)(w + off); off += n * 8; return p; };
    auto alloc_i  = [&](size_t n) { int*    p = (int*)(w + off);    off += n * 4; return p; };
    float* P[8]; for (int i = 0; i < 8; ++i) P[i] = alloc_f((size_t)nn[i] * PS);
    float* z[8]; for (int e = 0; e < 8; ++e) z[e] = alloc_f((size_t)rows[e] * PS);
    float* r[8]; for (int e = 0; e < 8; ++e) r[e] = alloc_f((size_t)rows[e] * 2);
    float2* sb[8]; for (int e = 0; e < 8; ++e) sb[e] = alloc_f2((size_t)ncol[e]);
    float2* sa[8]; for (int e = 0; e < 8; ++e) sa[e] = alloc_f2((size_t)rows[e]);
    int* cnt = alloc_i((size_t)totalRows);
    int nchunks = cdiv(totalRows, 1024);
    int* bsum = alloc_i((size_t)nchunks);
    unsigned short* colind = (unsigned short*)(w + off);
    off += (size_t)totE * 2;
    (void)ws_size;

    const int B = 256;

    // ---- flat CSR build ----
    hipMemsetAsync(cnt, 0, (size_t)totalRows * 4, stream);
    EdgeArgs EA;
    for (int e = 0; e < 8; ++e) {
        EA.rows[e] = edge[e]; EA.cols[e] = edge[e] + E[e];
        EA.rowbase[e] = rowbase[e];
        EA.ebase[e] = ebase[e];
    }
    EA.ebase[8] = ebase[8];
    EA.cnt = cnt; EA.colind = colind;
    hist_kernel<<<cdiv(totE, B), B, 0, stream>>>(EA);
    scan_part_kernel<<<nchunks, 1024, 0, stream>>>(cnt, totalRows, bsum);
    scan_bsum_kernel<<<1, 1024, 0, stream>>>(bsum, nchunks);
    add_off_kernel<<<nchunks, 1024, 0, stream>>>(cnt, totalRows, bsum);
    scatter_kernel<<<cdiv(totE, B), B, 0, stream>>>(EA);   // leaves cnt[w] = inclusive end

    // ---- fac ----
    FacArgs FA;
    FA.base[0] = 0;
    for (int i = 0; i < 8; ++i) { FA.emb[i] = emb[i]; FA.P[i] = P[i]; FA.base[i + 1] = FA.base[i] + nn[i]; }
    FA.Wtk = Wtk;
    fac_kernel<<<cdiv(FA.base[8], B), B, 0, stream>>>(FA);

    // ---- static sb (rels 2..7) once ----
    SbArgs SBs;
    SBs.base[0] = 0;
    for (int e = 2; e < 8; ++e) {
        SBs.Pb[e - 2] = P[bIdx[e]];
        SBs.at[e - 2] = at + (size_t)e * KF * DD;
        SBs.sb[e - 2] = sb[e];
        SBs.base[e - 1] = SBs.base[e - 2] + ncol[e];
    }
    sb_kernel<<<cdiv(SBs.base[6], B), B, 0, stream>>>(SBs);

    // ---- initial dynamic scores (sa all rels + sb0/sb1) ----
    ScoreArgs SC;
    SC.P0 = P[0]; SC.P1 = P[1]; SC.at = at;
    for (int e = 0; e < 8; ++e) SC.sa[e] = sa[e];
    SC.sb0 = sb[0]; SC.sb1 = sb[1];
    SC.n0 = nn[0]; SC.n1 = nn[1];
    score01_kernel<<<cdiv(nn[0] + nn[1], B), B, 0, stream>>>(SC);

    // ---- iterations ----
    PhaseArgs PA;
    PA.rowptr = cnt; PA.colind = colind;
    for (int e = 0; e < 8; ++e) {
        PA.Pb[e] = P[bIdx[e]];
        PA.q[e]  = q + (size_t)e * DK;
        PA.sa[e] = sa[e]; PA.sb[e] = sb[e];
        PA.z[e] = z[e]; PA.r[e] = r[e];
        PA.rowbase[e] = rowbase[e];
    }
    PA.rowbase[8] = rowbase[8];
    PA.W = W;
    EgoArgs GA;
    GA.P0 = P[0]; GA.P1 = P[1]; GA.n0 = nn[0]; GA.n1 = nn[1];
    for (int e = 0; e < 8; ++e) { GA.zz[e] = z[e]; GA.rr[e] = r[e]; GA.sa[e] = sa[e]; }
    GA.at = at;
    GA.sb0 = sb[0]; GA.sb1 = sb[1];
    GA.outp = nullptr;

    for (int it = 0; it < ITERS; ++it) {
        phase_kernel<<<cdiv(totalRows, WPB), WPB * 64, 0, stream>>>(PA, totalRows);
        GA.outp = (it == ITERS - 1) ? out : nullptr;
        ego_kernel<<<cdiv(nn[0] + nn[1], B), B, 0, stream>>>(GA);
    }
}

// Round 9
// 1459.099 us; speedup vs baseline: 1.7897x; 1.1068x over previous
//
#include <hip/hip_runtime.h>
#include <math.h>

// GraphEncoder v16 = v15 (1615us, best) + CSR build restructure.
// v15 counters: scatter_kernel = 245us with WRITE_SIZE 200MB for a 5.2MB
// colind (scattered u16 writes -> full-line writebacks ping-ponging across
// 8 incoherent XCD L2s) + a redundant second 2.6M-atomic pass.
// v16 single-atomic-pass build:
//   rank_kernel:  rank[e] = atomicAdd(cnt[grow]) (+coalesced rank write)
//   scan over totalRows+1 -> cnt = exclusive starts, cnt[totalRows] = totE
//   place_kernel: colind[cnt[grow]+rank[e]] = col[e]   (no atomics)
// Phase switches to beg=rowptr[w], end=rowptr[w+1]. Phase/ego otherwise
// identical to v15 (verified: sub4<13 mask, offset-shuffle unroll-4 t-loop,
// LDS-broadcast epilogue, fused scores/out in ego).

#define KF 2
#define DK 25
#define DD 50
#define PS 52   // padded P/z row stride: 208 B = 13 float4
#define ITERS 4
#define WPB 4

static __device__ __forceinline__ float leakyf(float x) { return x > 0.f ? x : 0.2f * x; }

static __device__ __forceinline__ float fast_tanhf(float x) {
    float e = __expf(2.f * x);
    return 1.f - 2.f * __builtin_amdgcn_rcpf(e + 1.f);
}

// at[e] is [2][50]: factor k at a+k*50; 0..24 row-side, 25..49 col-side.
static __device__ __forceinline__ float2 score_row50(const float* p, const float* a) {
    float s0 = 0.f, s1 = 0.f;
    #pragma unroll
    for (int f = 0; f < DK; ++f) {
        s0 = fmaf(p[f],      a[f],      s0);
        s1 = fmaf(p[DK + f], a[50 + f], s1);
    }
    return make_float2(s0, s1);
}
static __device__ __forceinline__ float2 score_col50(const float* p, const float* a) {
    float s0 = 0.f, s1 = 0.f;
    #pragma unroll
    for (int f = 0; f < DK; ++f) {
        s0 = fmaf(p[f],      a[25 + f], s0);
        s1 = fmaf(p[DK + f], a[75 + f], s1);
    }
    return make_float2(s0, s1);
}

// ---------------- fac ----------------
struct FacArgs { const float* emb[8]; float* P[8]; const float* Wtk; int base[9]; };

__global__ void fac_kernel(FacArgs A) {
    int g = blockIdx.x * blockDim.x + threadIdx.x;
    if (g >= A.base[8]) return;
    int ty = 0;
    while (g >= A.base[ty + 1]) ++ty;
    int node = g - A.base[ty];
    const float* er = A.emb[ty] + (size_t)node * DD;
    const float* Wt = A.Wtk + (size_t)ty * KF * DD * DK;
    float x[DD];
    #pragma unroll
    for (int d = 0; d < DD; ++d) x[d] = er[d];
    float out[DD];
    #pragma unroll
    for (int k = 0; k < KF; ++k) {
        const float* Wk = Wt + k * DD * DK;
        float nrm = 0.f;
        for (int f = 0; f < DK; ++f) {
            float acc = 0.f;
            for (int d = 0; d < DD; ++d) acc = fmaf(x[d], Wk[d * DK + f], acc);
            acc = leakyf(acc);
            out[k * DK + f] = acc;
            nrm = fmaf(acc, acc, nrm);
        }
        float inv = 1.f / fmaxf(sqrtf(nrm), 1e-12f);
        for (int f = 0; f < DK; ++f) out[k * DK + f] *= inv;
    }
    float* Pr = A.P[ty] + (size_t)node * PS;
    #pragma unroll
    for (int j = 0; j < DD; ++j) Pr[j] = out[j];
    Pr[50] = 0.f; Pr[51] = 0.f;
}

// ---------------- flat CSR build (single atomic pass) ----------------
struct EdgeArgs {
    const int* rows[8]; const int* cols[8];
    int* cnt;                  // [totalRows+1] counts -> exclusive starts
    unsigned* rank;            // [totE] within-row rank
    unsigned short* colind;    // [totE] flat
    int ebase[9];
    int rowbase[8];
};

__global__ void rank_kernel(EdgeArgs A) {
    int g = blockIdx.x * blockDim.x + threadIdx.x;
    if (g >= A.ebase[8]) return;
    int rel = 0;
    while (g >= A.ebase[rel + 1]) ++rel;
    int e = g - A.ebase[rel];
    A.rank[g] = (unsigned)atomicAdd(&A.cnt[A.rowbase[rel] + A.rows[rel][e]], 1);
}

// 3-kernel hierarchical exclusive scan over cnt[0..n)
__global__ __launch_bounds__(1024) void scan_part_kernel(int* a, int n, int* bsum) {
    __shared__ int lds[1024];
    int tid = threadIdx.x;
    int i = blockIdx.x * 1024 + tid;
    int v = (i < n) ? a[i] : 0;
    lds[tid] = v;
    __syncthreads();
    int x = v;
    for (int off = 1; off < 1024; off <<= 1) {
        int y = (tid >= off) ? lds[tid - off] : 0;
        __syncthreads();
        x += y;
        lds[tid] = x;
        __syncthreads();
    }
    if (i < n) a[i] = x - v;              // exclusive within chunk
    if (tid == 1023) bsum[blockIdx.x] = x; // chunk total
}

__global__ __launch_bounds__(1024) void scan_bsum_kernel(int* bsum, int nb) {
    __shared__ int lds[1024];
    int tid = threadIdx.x;
    int v = (tid < nb) ? bsum[tid] : 0;
    lds[tid] = v;
    __syncthreads();
    int x = v;
    for (int off = 1; off < 1024; off <<= 1) {
        int y = (tid >= off) ? lds[tid - off] : 0;
        __syncthreads();
        x += y;
        lds[tid] = x;
        __syncthreads();
    }
    if (tid < nb) bsum[tid] = x - v;      // exclusive chunk offsets
}

__global__ __launch_bounds__(1024) void add_off_kernel(int* a, int n, const int* bsum) {
    int i = blockIdx.x * 1024 + threadIdx.x;
    if (i < n) a[i] += bsum[blockIdx.x];
}

// place: no atomics; p = start[grow] + rank[e]
__global__ void place_kernel(EdgeArgs A) {
    int g = blockIdx.x * blockDim.x + threadIdx.x;
    if (g >= A.ebase[8]) return;
    int rel = 0;
    while (g >= A.ebase[rel + 1]) ++rel;
    int e = g - A.ebase[rel];
    int p = A.cnt[A.rowbase[rel] + A.rows[rel][e]] + (int)A.rank[g];
    A.colind[p] = (unsigned short)A.cols[rel][e];
}

// ---------------- sb init for static relations 2..7 ----------------
struct SbArgs { const float* Pb[6]; const float* at[6]; float2* sb[6]; int base[7]; };

__global__ void sb_kernel(SbArgs A) {
    int g = blockIdx.x * blockDim.x + threadIdx.x;
    if (g >= A.base[6]) return;
    int rel = 0;
    while (g >= A.base[rel + 1]) ++rel;
    int c = g - A.base[rel];
    const float* p = A.Pb[rel] + (size_t)c * PS;
    A.sb[rel][c] = score_col50(p, A.at[rel]);
}

// ---------------- score01: INITIAL sa (all rels) + sb0/sb1 (after fac) ----------------
struct ScoreArgs {
    const float* P0; const float* P1;
    const float* at;
    float2* sa[8]; float2* sb0; float2* sb1;
    int n0, n1;
};

__global__ void score01_kernel(ScoreArgs A) {
    int g = blockIdx.x * blockDim.x + threadIdx.x;
    if (g >= A.n0 + A.n1) return;
    if (g < A.n0) {
        const float* p = A.P0 + (size_t)g * PS;
        float pr[DD];
        #pragma unroll
        for (int j = 0; j < DD; ++j) pr[j] = p[j];
        A.sa[0][g] = score_row50(pr, A.at + 0);
        A.sb1[g]   = score_col50(pr, A.at + 100);
    } else {
        int node = g - A.n0;
        const float* p = A.P1 + (size_t)node * PS;
        float pr[DD];
        #pragma unroll
        for (int j = 0; j < DD; ++j) pr[j] = p[j];
        #pragma unroll
        for (int e = 1; e < 8; ++e) A.sa[e][node] = score_row50(pr, A.at + e * 100);
        A.sb0[node] = score_col50(pr, A.at + 0);
    }
}

// ---------------- fused phase (gather + LDS epilogue; offset-shuffle, unroll 4) ----------------
struct PhaseArgs {
    const int* rowptr;               // [totalRows+1] exclusive starts (flat)
    const unsigned short* colind;    // flat
    const float* Pb[8];
    const float* q[8];
    const float2* sa[8]; const float2* sb[8];
    float* z[8]; float* r[8];
    const float* W;
    int rowbase[9];
};

__global__ __launch_bounds__(WPB * 64) void phase_kernel(PhaseArgs A, int totalRows) {
    __shared__ float Wsh[DK * DK];
    __shared__ float zsh[WPB][DD];
    for (int i = threadIdx.x; i < DK * DK; i += WPB * 64) Wsh[i] = A.W[i];
    __syncthreads();

    int wslot = threadIdx.x >> 6;
    int wave = blockIdx.x * WPB + wslot;
    int lane = threadIdx.x & 63;
    if (wave >= totalRows) return;
    int rel = 0;
    while (wave >= A.rowbase[rel + 1]) ++rel;
    int u = wave - A.rowbase[rel];

    const unsigned short* colind = A.colind;
    const char* Pb = (const char*)A.Pb[rel];
    const float* qv = A.q[rel];
    const float2* sb = A.sb[rel];
    float2 h = A.sa[rel][u];
    int beg = A.rowptr[wave];
    int end = A.rowptr[wave + 1];

    bool act = lane < DD;
    int grp4 = lane >> 4, sub4 = lane & 15;
    bool ld = sub4 < 13;   // P row is 13 float4; 16 would touch a 5th line
    float ssum = 0.f;
    float4 a4 = make_float4(0.f, 0.f, 0.f, 0.f);

    for (int base = beg; base < end; base += 64) {
        int idx = base + lane;
        bool vld = idx < end;
        int cb = vld ? (int)colind[idx] : 0;
        unsigned ob = (unsigned)cb * (unsigned)(PS * 4);   // byte offset, 64-wide
        float evl = 0.f;
        if (vld) {
            float2 sc = sb[cb];
            evl = __expf(0.5f * (fmaxf(h.x + sc.x, 0.f) + fmaxf(h.y + sc.y, 0.f)));
        }
        ssum += evl;
        int nb = min(64, end - base);
        #pragma unroll 4
        for (int t = 0; t < nb; t += 4) {
            int srcl = t + grp4;
            unsigned o4 = __shfl(ob, srcl);
            float ev = __shfl(evl, srcl);
            if (ld) {
                const float4* pc = (const float4*)(Pb + o4);
                float4 v = pc[sub4];
                a4.x = fmaf(ev, v.x, a4.x);
                a4.y = fmaf(ev, v.y, a4.y);
                a4.z = fmaf(ev, v.z, a4.z);
                a4.w = fmaf(ev, v.w, a4.w);
            }
        }
    }
    #pragma unroll
    for (int off = 32; off >= 16; off >>= 1) {
        a4.x += __shfl_xor(a4.x, off);
        a4.y += __shfl_xor(a4.y, off);
        a4.z += __shfl_xor(a4.z, off);
        a4.w += __shfl_xor(a4.w, off);
    }
    #pragma unroll
    for (int off = 32; off; off >>= 1) ssum += __shfl_xor(ssum, off);

    int src = lane >> 2;
    float fx = __shfl(a4.x, src), fy = __shfl(a4.y, src);
    float fz = __shfl(a4.z, src), fw = __shfl(a4.w, src);
    float za = (lane & 1) ? ((lane & 2) ? fw : fy) : ((lane & 2) ? fz : fx);

    float inv = (ssum > 0.f) ? (1.f / ssum) : 0.f;
    float zl = act ? leakyf(za * inv) : 0.f;

    // epilogue matvec via LDS broadcast reads (scalar o per lane, no arrays)
    if (act) zsh[wslot][lane] = zl;
    int fcol = act ? ((lane < DK) ? lane : (lane - DK)) : 0;
    int kbase = (act && lane >= DK) ? DK : 0;
    float o = 0.f;
    #pragma unroll
    for (int d = 0; d < DK; ++d)
        o = fmaf(zsh[wslot][kbase + d], Wsh[d * DK + fcol], o);

    float th = act ? fast_tanhf(o) * qv[fcol] : 0.f;
    float t0 = (lane < DK) ? th : 0.f;
    float t1 = th - t0;
    #pragma unroll
    for (int off = 32; off; off >>= 1) { t0 += __shfl_xor(t0, off); t1 += __shfl_xor(t1, off); }
    float m = fmaxf(t0, t1);
    float e0 = __expf(t0 - m), e1 = __expf(t1 - m);
    float rinv = 1.f / (e0 + e1);

    if (act) A.z[rel][(size_t)u * PS + lane] = o;
    if (lane == 0) {
        A.r[rel][(size_t)u * 2 + 0] = e0 * rinv;
        A.r[rel][(size_t)u * 2 + 1] = e1 * rinv;
    }
}

// ---------------- ego (float4 z loads + fused out + fused scores) ----------------
struct EgoArgs {
    float* P0; float* P1;
    const float* zz[8];   // PS stride
    const float* rr[8];
    const float* at;      // [8][2][50]
    float2* sa[8]; float2* sb0; float2* sb1;
    float* outp;          // non-null on last iteration (scores skipped then)
    int n0, n1;
};

__global__ __launch_bounds__(256) void ego_kernel(EgoArgs A) {
    int g = blockIdx.x * blockDim.x + threadIdx.x;
    if (g >= A.n0 + A.n1) return;
    float acc[DD];
    bool is0 = g < A.n0;
    int node = is0 ? g : g - A.n0;
    float* Pr = (is0 ? A.P0 : A.P1) + (size_t)node * PS;
    {
        const float4* p4 = (const float4*)Pr;
        #pragma unroll
        for (int t = 0; t < 12; ++t) {
            float4 v = p4[t];
            acc[4 * t] = v.x; acc[4 * t + 1] = v.y; acc[4 * t + 2] = v.z; acc[4 * t + 3] = v.w;
        }
        acc[48] = Pr[48]; acc[49] = Pr[49];
    }
    int jbeg = is0 ? 0 : 1, jend = is0 ? 1 : 8;
    #pragma unroll 1
    for (int j = jbeg; j < jend; ++j) {
        const float* zr = A.zz[j] + (size_t)node * PS;
        float r0 = A.rr[j][(size_t)node * 2], r1 = A.rr[j][(size_t)node * 2 + 1];
        const float4* z4 = (const float4*)zr;
        #pragma unroll
        for (int t = 0; t < 12; ++t) {
            float4 v = z4[t];
            acc[4 * t]     = fmaf(v.x, (4 * t     < DK) ? r0 : r1, acc[4 * t]);
            acc[4 * t + 1] = fmaf(v.y, (4 * t + 1 < DK) ? r0 : r1, acc[4 * t + 1]);
            acc[4 * t + 2] = fmaf(v.z, (4 * t + 2 < DK) ? r0 : r1, acc[4 * t + 2]);
            acc[4 * t + 3] = fmaf(v.w, (4 * t + 3 < DK) ? r0 : r1, acc[4 * t + 3]);
        }
        acc[48] = fmaf(zr[48], r1, acc[48]);
        acc[49] = fmaf(zr[49], r1, acc[49]);
    }
    // l2norm per factor, store
    #pragma unroll
    for (int k = 0; k < KF; ++k) {
        float nrm = 0.f;
        #pragma unroll
        for (int f = 0; f < DK; ++f) nrm = fmaf(acc[k * DK + f], acc[k * DK + f], nrm);
        float inv = 1.f / fmaxf(sqrtf(nrm), 1e-12f);
        #pragma unroll
        for (int f = 0; f < DK; ++f) acc[k * DK + f] *= inv;
    }
    #pragma unroll
    for (int f = 0; f < DD; ++f) Pr[f] = acc[f];

    if (A.outp) {
        float* dst = A.outp + (size_t)g * DD;
        #pragma unroll
        for (int f = 0; f < DD; ++f) dst[f] = acc[f];
        return;
    }

    // scores from the new P row (registers) — replaces in-loop score01
    if (is0) {
        A.sa[0][node] = score_row50(acc, A.at + 0);
        A.sb1[node]   = score_col50(acc, A.at + 100);
    } else {
        #pragma unroll 1
        for (int e = 1; e < 8; ++e) A.sa[e][node] = score_row50(acc, A.at + e * 100);
        A.sb0[node] = score_col50(acc, A.at + 0);
    }
}

static inline int cdiv(int a, int b) { return (a + b - 1) / b; }

extern "C" void kernel_launch(void* const* d_in, const int* in_sizes, int n_in,
                              void* d_out, int out_size, void* d_ws, size_t ws_size,
                              hipStream_t stream) {
    const int* edge[8];
    int E[8];
    for (int e = 0; e < 8; ++e) { edge[e] = (const int*)d_in[e]; E[e] = in_sizes[e] / 2; }
    const float* emb[8];
    int nn[8];
    for (int i = 0; i < 8; ++i) { emb[i] = (const float*)d_in[8 + i]; nn[i] = in_sizes[8 + i] / DD; }
    const float* Wtk = (const float*)d_in[16];
    const float* at  = (const float*)d_in[17];
    const float* W   = (const float*)d_in[18];
    const float* q   = (const float*)d_in[19];
    float* out = (float*)d_out;

    static const int aIdx[8] = {0, 1, 1, 1, 1, 1, 1, 1};
    static const int bIdx[8] = {1, 0, 2, 3, 4, 5, 6, 7};
    int rows[8], ncol[8];
    for (int e = 0; e < 8; ++e) { rows[e] = nn[aIdx[e]]; ncol[e] = nn[bIdx[e]]; }
    int rowbase[9];
    rowbase[0] = 0;
    for (int e = 0; e < 8; ++e) rowbase[e + 1] = rowbase[e] + rows[e];
    int totalRows = rowbase[8];
    int ebase[9];
    ebase[0] = 0;
    for (int e = 0; e < 8; ++e) ebase[e + 1] = ebase[e] + E[e];
    int totE = ebase[8];

    // ---- workspace: P(52), z(52), r, sb, sa, cnt(+1), bsum, rank, colind ----
    char* w = (char*)d_ws;
    size_t off = 0;
    auto alloc_f  = [&](size_t n) { float*  p = (float*)(w + off);  off += n * 4; return p; };
    auto alloc_f2 = [&](size_t n) { float2* p = (float2*)(w + off); off += n * 8; return p; };
    auto alloc_i  = [&](size_t n) { int*    p = (int*)(w + off);    off += n * 4; return p; };
    float* P[8]; for (int i = 0; i < 8; ++i) P[i] = alloc_f((size_t)nn[i] * PS);
    float* z[8]; for (int e = 0; e < 8; ++e) z[e] = alloc_f((size_t)rows[e] * PS);
    float* r[8]; for (int e = 0; e < 8; ++e) r[e] = alloc_f((size_t)rows[e] * 2);
    float2* sb[8]; for (int e = 0; e < 8; ++e) sb[e] = alloc_f2((size_t)ncol[e]);
    float2* sa[8]; for (int e = 0; e < 8; ++e) sa[e] = alloc_f2((size_t)rows[e]);
    int nScan = totalRows + 1;
    int* cnt = alloc_i((size_t)nScan);
    int nchunks = cdiv(nScan, 1024);
    int* bsum = alloc_i((size_t)nchunks);
    unsigned* rank = (unsigned*)alloc_i((size_t)totE);
    unsigned short* colind = (unsigned short*)(w + off);
    off += (size_t)totE * 2;
    (void)ws_size;

    const int B = 256;

    // ---- flat CSR build (single atomic pass) ----
    hipMemsetAsync(cnt, 0, (size_t)nScan * 4, stream);
    EdgeArgs EA;
    for (int e = 0; e < 8; ++e) {
        EA.rows[e] = edge[e]; EA.cols[e] = edge[e] + E[e];
        EA.rowbase[e] = rowbase[e];
        EA.ebase[e] = ebase[e];
    }
    EA.ebase[8] = ebase[8];
    EA.cnt = cnt; EA.rank = rank; EA.colind = colind;
    rank_kernel<<<cdiv(totE, B), B, 0, stream>>>(EA);
    scan_part_kernel<<<nchunks, 1024, 0, stream>>>(cnt, nScan, bsum);
    scan_bsum_kernel<<<1, 1024, 0, stream>>>(bsum, nchunks);
    add_off_kernel<<<nchunks, 1024, 0, stream>>>(cnt, nScan, bsum);
    place_kernel<<<cdiv(totE, B), B, 0, stream>>>(EA);  // cnt untouched: exclusive starts

    // ---- fac ----
    FacArgs FA;
    FA.base[0] = 0;
    for (int i = 0; i < 8; ++i) { FA.emb[i] = emb[i]; FA.P[i] = P[i]; FA.base[i + 1] = FA.base[i] + nn[i]; }
    FA.Wtk = Wtk;
    fac_kernel<<<cdiv(FA.base[8], B), B, 0, stream>>>(FA);

    // ---- static sb (rels 2..7) once ----
    SbArgs SBs;
    SBs.base[0] = 0;
    for (int e = 2; e < 8; ++e) {
        SBs.Pb[e - 2] = P[bIdx[e]];
        SBs.at[e - 2] = at + (size_t)e * KF * DD;
        SBs.sb[e - 2] = sb[e];
        SBs.base[e - 1] = SBs.base[e - 2] + ncol[e];
    }
    sb_kernel<<<cdiv(SBs.base[6], B), B, 0, stream>>>(SBs);

    // ---- initial dynamic scores (sa all rels + sb0/sb1) ----
    ScoreArgs SC;
    SC.P0 = P[0]; SC.P1 = P[1]; SC.at = at;
    for (int e = 0; e < 8; ++e) SC.sa[e] = sa[e];
    SC.sb0 = sb[0]; SC.sb1 = sb[1];
    SC.n0 = nn[0]; SC.n1 = nn[1];
    score01_kernel<<<cdiv(nn[0] + nn[1], B), B, 0, stream>>>(SC);

    // ---- iterations ----
    PhaseArgs PA;
    PA.rowptr = cnt; PA.colind = colind;
    for (int e = 0; e < 8; ++e) {
        PA.Pb[e] = P[bIdx[e]];
        PA.q[e]  = q + (size_t)e * DK;
        PA.sa[e] = sa[e]; PA.sb[e] = sb[e];
        PA.z[e] = z[e]; PA.r[e] = r[e];
        PA.rowbase[e] = rowbase[e];
    }
    PA.rowbase[8] = rowbase[8];
    PA.W = W;
    EgoArgs GA;
    GA.P0 = P[0]; GA.P1 = P[1]; GA.n0 = nn[0]; GA.n1 = nn[1];
    for (int e = 0; e < 8; ++e) { GA.zz[e] = z[e]; GA.rr[e] = r[e]; GA.sa[e] = sa[e]; }
    GA.at = at;
    GA.sb0 = sb[0]; GA.sb1 = sb[1];
    GA.outp = nullptr;

    for (int it = 0; it < ITERS; ++it) {
        phase_kernel<<<cdiv(totalRows, WPB), WPB * 64, 0, stream>>>(PA, totalRows);
        GA.outp = (it == ITERS - 1) ? out : nullptr;
        ego_kernel<<<cdiv(nn[0] + nn[1], B), B, 0, stream>>>(GA);
    }
}

// Round 13
// 1444.397 us; speedup vs baseline: 1.8079x; 1.0102x over previous
//
#include <hip/hip_runtime.h>
#include <math.h>

// GraphEncoder v19 (resubmission; round-12 run was an infra failure —
// "MI355X container failed twice", bench never executed).
// v19 = EXACT v16 (passed, 1459us) + ONE provably-safe change:
// last-iteration ego skips the dead P writeback (P never read after final
// phase; out carries the result). A store removal cannot fault; if this
// aborts again the cause is environmental (consistent with v17/v18's
// anomalous infra timing: 748s/817s pushes, 121s acquires).

#define KF 2
#define DK 25
#define DD 50
#define PS 52   // padded P/z row stride: 208 B = 13 float4
#define ITERS 4
#define WPB 4

static __device__ __forceinline__ float leakyf(float x) { return x > 0.f ? x : 0.2f * x; }

static __device__ __forceinline__ float fast_tanhf(float x) {
    float e = __expf(2.f * x);
    return 1.f - 2.f * __builtin_amdgcn_rcpf(e + 1.f);
}

// at[e] is [2][50]: factor k at a+k*50; 0..24 row-side, 25..49 col-side.
static __device__ __forceinline__ float2 score_row50(const float* p, const float* a) {
    float s0 = 0.f, s1 = 0.f;
    #pragma unroll
    for (int f = 0; f < DK; ++f) {
        s0 = fmaf(p[f],      a[f],      s0);
        s1 = fmaf(p[DK + f], a[50 + f], s1);
    }
    return make_float2(s0, s1);
}
static __device__ __forceinline__ float2 score_col50(const float* p, const float* a) {
    float s0 = 0.f, s1 = 0.f;
    #pragma unroll
    for (int f = 0; f < DK; ++f) {
        s0 = fmaf(p[f],      a[25 + f], s0);
        s1 = fmaf(p[DK + f], a[75 + f], s1);
    }
    return make_float2(s0, s1);
}

// ---------------- fac ----------------
struct FacArgs { const float* emb[8]; float* P[8]; const float* Wtk; int base[9]; };

__global__ void fac_kernel(FacArgs A) {
    int g = blockIdx.x * blockDim.x + threadIdx.x;
    if (g >= A.base[8]) return;
    int ty = 0;
    while (g >= A.base[ty + 1]) ++ty;
    int node = g - A.base[ty];
    const float* er = A.emb[ty] + (size_t)node * DD;
    const float* Wt = A.Wtk + (size_t)ty * KF * DD * DK;
    float x[DD];
    #pragma unroll
    for (int d = 0; d < DD; ++d) x[d] = er[d];
    float out[DD];
    #pragma unroll
    for (int k = 0; k < KF; ++k) {
        const float* Wk = Wt + k * DD * DK;
        float nrm = 0.f;
        for (int f = 0; f < DK; ++f) {
            float acc = 0.f;
            for (int d = 0; d < DD; ++d) acc = fmaf(x[d], Wk[d * DK + f], acc);
            acc = leakyf(acc);
            out[k * DK + f] = acc;
            nrm = fmaf(acc, acc, nrm);
        }
        float inv = 1.f / fmaxf(sqrtf(nrm), 1e-12f);
        for (int f = 0; f < DK; ++f) out[k * DK + f] *= inv;
    }
    float* Pr = A.P[ty] + (size_t)node * PS;
    #pragma unroll
    for (int j = 0; j < DD; ++j) Pr[j] = out[j];
    Pr[50] = 0.f; Pr[51] = 0.f;
}

// ---------------- flat CSR build (single atomic pass) ----------------
struct EdgeArgs {
    const int* rows[8]; const int* cols[8];
    int* cnt;                  // [totalRows+1] counts -> exclusive starts
    unsigned* rank;            // [totE] within-row rank
    unsigned short* colind;    // [totE] flat
    int ebase[9];
    int rowbase[8];
};

__global__ void rank_kernel(EdgeArgs A) {
    int g = blockIdx.x * blockDim.x + threadIdx.x;
    if (g >= A.ebase[8]) return;
    int rel = 0;
    while (g >= A.ebase[rel + 1]) ++rel;
    int e = g - A.ebase[rel];
    A.rank[g] = (unsigned)atomicAdd(&A.cnt[A.rowbase[rel] + A.rows[rel][e]], 1);
}

// 3-kernel hierarchical exclusive scan over cnt[0..n)
__global__ __launch_bounds__(1024) void scan_part_kernel(int* a, int n, int* bsum) {
    __shared__ int lds[1024];
    int tid = threadIdx.x;
    int i = blockIdx.x * 1024 + tid;
    int v = (i < n) ? a[i] : 0;
    lds[tid] = v;
    __syncthreads();
    int x = v;
    for (int off = 1; off < 1024; off <<= 1) {
        int y = (tid >= off) ? lds[tid - off] : 0;
        __syncthreads();
        x += y;
        lds[tid] = x;
        __syncthreads();
    }
    if (i < n) a[i] = x - v;              // exclusive within chunk
    if (tid == 1023) bsum[blockIdx.x] = x; // chunk total
}

__global__ __launch_bounds__(1024) void scan_bsum_kernel(int* bsum, int nb) {
    __shared__ int lds[1024];
    int tid = threadIdx.x;
    int v = (tid < nb) ? bsum[tid] : 0;
    lds[tid] = v;
    __syncthreads();
    int x = v;
    for (int off = 1; off < 1024; off <<= 1) {
        int y = (tid >= off) ? lds[tid - off] : 0;
        __syncthreads();
        x += y;
        lds[tid] = x;
        __syncthreads();
    }
    if (tid < nb) bsum[tid] = x - v;      // exclusive chunk offsets
}

__global__ __launch_bounds__(1024) void add_off_kernel(int* a, int n, const int* bsum) {
    int i = blockIdx.x * 1024 + threadIdx.x;
    if (i < n) a[i] += bsum[blockIdx.x];
}

// place: no atomics; p = start[grow] + rank[e]
__global__ void place_kernel(EdgeArgs A) {
    int g = blockIdx.x * blockDim.x + threadIdx.x;
    if (g >= A.ebase[8]) return;
    int rel = 0;
    while (g >= A.ebase[rel + 1]) ++rel;
    int e = g - A.ebase[rel];
    int p = A.cnt[A.rowbase[rel] + A.rows[rel][e]] + (int)A.rank[g];
    A.colind[p] = (unsigned short)A.cols[rel][e];
}

// ---------------- sb init for static relations 2..7 ----------------
struct SbArgs { const float* Pb[6]; const float* at[6]; float2* sb[6]; int base[7]; };

__global__ void sb_kernel(SbArgs A) {
    int g = blockIdx.x * blockDim.x + threadIdx.x;
    if (g >= A.base[6]) return;
    int rel = 0;
    while (g >= A.base[rel + 1]) ++rel;
    int c = g - A.base[rel];
    const float* p = A.Pb[rel] + (size_t)c * PS;
    A.sb[rel][c] = score_col50(p, A.at[rel]);
}

// ---------------- score01: INITIAL sa (all rels) + sb0/sb1 (after fac) ----------------
struct ScoreArgs {
    const float* P0; const float* P1;
    const float* at;
    float2* sa[8]; float2* sb0; float2* sb1;
    int n0, n1;
};

__global__ void score01_kernel(ScoreArgs A) {
    int g = blockIdx.x * blockDim.x + threadIdx.x;
    if (g >= A.n0 + A.n1) return;
    if (g < A.n0) {
        const float* p = A.P0 + (size_t)g * PS;
        float pr[DD];
        #pragma unroll
        for (int j = 0; j < DD; ++j) pr[j] = p[j];
        A.sa[0][g] = score_row50(pr, A.at + 0);
        A.sb1[g]   = score_col50(pr, A.at + 100);
    } else {
        int node = g - A.n0;
        const float* p = A.P1 + (size_t)node * PS;
        float pr[DD];
        #pragma unroll
        for (int j = 0; j < DD; ++j) pr[j] = p[j];
        #pragma unroll
        for (int e = 1; e < 8; ++e) A.sa[e][node] = score_row50(pr, A.at + e * 100);
        A.sb0[node] = score_col50(pr, A.at + 0);
    }
}

// ---------------- fused phase (gather + LDS epilogue) ----------------
struct PhaseArgs {
    const int* rowptr;               // [totalRows+1] exclusive starts (flat)
    const unsigned short* colind;    // flat
    const float* Pb[8];
    const float* q[8];
    const float2* sa[8]; const float2* sb[8];
    float* z[8]; float* r[8];
    const float* W;
    int rowbase[9];
};

__global__ __launch_bounds__(WPB * 64) void phase_kernel(PhaseArgs A, int totalRows) {
    __shared__ float Wsh[DK * DK];
    __shared__ float zsh[WPB][DD];
    for (int i = threadIdx.x; i < DK * DK; i += WPB * 64) Wsh[i] = A.W[i];
    __syncthreads();

    int wslot = threadIdx.x >> 6;
    int wave = blockIdx.x * WPB + wslot;
    int lane = threadIdx.x & 63;
    if (wave >= totalRows) return;
    int rel = 0;
    while (wave >= A.rowbase[rel + 1]) ++rel;
    int u = wave - A.rowbase[rel];

    const unsigned short* colind = A.colind;
    const char* Pb = (const char*)A.Pb[rel];
    const float* qv = A.q[rel];
    const float2* sb = A.sb[rel];
    float2 h = A.sa[rel][u];
    int beg = A.rowptr[wave];
    int end = A.rowptr[wave + 1];

    bool act = lane < DD;
    int grp4 = lane >> 4, sub4 = lane & 15;
    bool ld = sub4 < 13;   // P row is 13 float4; 16 would touch a 5th line
    float ssum = 0.f;
    float4 a4 = make_float4(0.f, 0.f, 0.f, 0.f);

    for (int base = beg; base < end; base += 64) {
        int idx = base + lane;
        bool vld = idx < end;
        int cb = vld ? (int)colind[idx] : 0;
        unsigned ob = (unsigned)cb * (unsigned)(PS * 4);   // byte offset, 64-wide
        float evl = 0.f;
        if (vld) {
            float2 sc = sb[cb];
            evl = __expf(0.5f * (fmaxf(h.x + sc.x, 0.f) + fmaxf(h.y + sc.y, 0.f)));
        }
        ssum += evl;
        int nb = min(64, end - base);
        #pragma unroll 4
        for (int t = 0; t < nb; t += 4) {
            int srcl = t + grp4;
            unsigned o4 = __shfl(ob, srcl);
            float ev = __shfl(evl, srcl);
            if (ld) {
                const float4* pc = (const float4*)(Pb + o4);
                float4 v = pc[sub4];
                a4.x = fmaf(ev, v.x, a4.x);
                a4.y = fmaf(ev, v.y, a4.y);
                a4.z = fmaf(ev, v.z, a4.z);
                a4.w = fmaf(ev, v.w, a4.w);
            }
        }
    }
    #pragma unroll
    for (int off = 32; off >= 16; off >>= 1) {
        a4.x += __shfl_xor(a4.x, off);
        a4.y += __shfl_xor(a4.y, off);
        a4.z += __shfl_xor(a4.z, off);
        a4.w += __shfl_xor(a4.w, off);
    }
    #pragma unroll
    for (int off = 32; off; off >>= 1) ssum += __shfl_xor(ssum, off);

    int src = lane >> 2;
    float fx = __shfl(a4.x, src), fy = __shfl(a4.y, src);
    float fz = __shfl(a4.z, src), fw = __shfl(a4.w, src);
    float za = (lane & 1) ? ((lane & 2) ? fw : fy) : ((lane & 2) ? fz : fx);

    float inv = (ssum > 0.f) ? (1.f / ssum) : 0.f;
    float zl = act ? leakyf(za * inv) : 0.f;

    // epilogue matvec via LDS broadcast reads (scalar o per lane, no arrays)
    if (act) zsh[wslot][lane] = zl;
    int fcol = act ? ((lane < DK) ? lane : (lane - DK)) : 0;
    int kbase = (act && lane >= DK) ? DK : 0;
    float o = 0.f;
    #pragma unroll
    for (int d = 0; d < DK; ++d)
        o = fmaf(zsh[wslot][kbase + d], Wsh[d * DK + fcol], o);

    float th = act ? fast_tanhf(o) * qv[fcol] : 0.f;
    float t0 = (lane < DK) ? th : 0.f;
    float t1 = th - t0;
    #pragma unroll
    for (int off = 32; off; off >>= 1) { t0 += __shfl_xor(t0, off); t1 += __shfl_xor(t1, off); }
    float m = fmaxf(t0, t1);
    float e0 = __expf(t0 - m), e1 = __expf(t1 - m);
    float rinv = 1.f / (e0 + e1);

    if (act) A.z[rel][(size_t)u * PS + lane] = o;
    if (lane == 0) {
        A.r[rel][(size_t)u * 2 + 0] = e0 * rinv;
        A.r[rel][(size_t)u * 2 + 1] = e1 * rinv;
    }
}

// ---------------- ego (float4 z loads + fused out + fused scores) ----------------
struct EgoArgs {
    float* P0; float* P1;
    const float* zz[8];   // PS stride
    const float* rr[8];
    const float* at;      // [8][2][50]
    float2* sa[8]; float2* sb0; float2* sb1;
    float* outp;          // non-null on last iteration (P write + scores skipped)
    int n0, n1;
};

__global__ __launch_bounds__(256) void ego_kernel(EgoArgs A) {
    int g = blockIdx.x * blockDim.x + threadIdx.x;
    if (g >= A.n0 + A.n1) return;
    float acc[DD];
    bool is0 = g < A.n0;
    int node = is0 ? g : g - A.n0;
    float* Pr = (is0 ? A.P0 : A.P1) + (size_t)node * PS;
    {
        const float4* p4 = (const float4*)Pr;
        #pragma unroll
        for (int t = 0; t < 12; ++t) {
            float4 v = p4[t];
            acc[4 * t] = v.x; acc[4 * t + 1] = v.y; acc[4 * t + 2] = v.z; acc[4 * t + 3] = v.w;
        }
        acc[48] = Pr[48]; acc[49] = Pr[49];
    }
    int jbeg = is0 ? 0 : 1, jend = is0 ? 1 : 8;
    #pragma unroll 1
    for (int j = jbeg; j < jend; ++j) {
        const float* zr = A.zz[j] + (size_t)node * PS;
        float r0 = A.rr[j][(size_t)node * 2], r1 = A.rr[j][(size_t)node * 2 + 1];
        const float4* z4 = (const float4*)zr;
        #pragma unroll
        for (int t = 0; t < 12; ++t) {
            float4 v = z4[t];
            acc[4 * t]     = fmaf(v.x, (4 * t     < DK) ? r0 : r1, acc[4 * t]);
            acc[4 * t + 1] = fmaf(v.y, (4 * t + 1 < DK) ? r0 : r1, acc[4 * t + 1]);
            acc[4 * t + 2] = fmaf(v.z, (4 * t + 2 < DK) ? r0 : r1, acc[4 * t + 2]);
            acc[4 * t + 3] = fmaf(v.w, (4 * t + 3 < DK) ? r0 : r1, acc[4 * t + 3]);
        }
        acc[48] = fmaf(zr[48], r1, acc[48]);
        acc[49] = fmaf(zr[49], r1, acc[49]);
    }
    // l2norm per factor
    #pragma unroll
    for (int k = 0; k < KF; ++k) {
        float nrm = 0.f;
        #pragma unroll
        for (int f = 0; f < DK; ++f) nrm = fmaf(acc[k * DK + f], acc[k * DK + f], nrm);
        float inv = 1.f / fmaxf(sqrtf(nrm), 1e-12f);
        #pragma unroll
        for (int f = 0; f < DK; ++f) acc[k * DK + f] *= inv;
    }

    if (A.outp) {
        // last iteration: P is dead afterwards; write only the output row
        float* dst = A.outp + (size_t)g * DD;
        #pragma unroll
        for (int f = 0; f < DD; ++f) dst[f] = acc[f];
        return;
    }

    #pragma unroll
    for (int f = 0; f < DD; ++f) Pr[f] = acc[f];

    // scores from the new P row (registers)
    if (is0) {
        A.sa[0][node] = score_row50(acc, A.at + 0);
        A.sb1[node]   = score_col50(acc, A.at + 100);
    } else {
        #pragma unroll 1
        for (int e = 1; e < 8; ++e) A.sa[e][node] = score_row50(acc, A.at + e * 100);
        A.sb0[node] = score_col50(acc, A.at + 0);
    }
}

static inline int cdiv(int a, int b) { return (a + b - 1) / b; }

extern "C" void kernel_launch(void* const* d_in, const int* in_sizes, int n_in,
                              void* d_out, int out_size, void* d_ws, size_t ws_size,
                              hipStream_t stream) {
    const int* edge[8];
    int E[8];
    for (int e = 0; e < 8; ++e) { edge[e] = (const int*)d_in[e]; E[e] = in_sizes[e] / 2; }
    const float* emb[8];
    int nn[8];
    for (int i = 0; i < 8; ++i) { emb[i] = (const float*)d_in[8 + i]; nn[i] = in_sizes[8 + i] / DD; }
    const float* Wtk = (const float*)d_in[16];
    const float* at  = (const float*)d_in[17];
    const float* W   = (const float*)d_in[18];
    const float* q   = (const float*)d_in[19];
    float* out = (float*)d_out;

    static const int aIdx[8] = {0, 1, 1, 1, 1, 1, 1, 1};
    static const int bIdx[8] = {1, 0, 2, 3, 4, 5, 6, 7};
    int rows[8], ncol[8];
    for (int e = 0; e < 8; ++e) { rows[e] = nn[aIdx[e]]; ncol[e] = nn[bIdx[e]]; }
    int rowbase[9];
    rowbase[0] = 0;
    for (int e = 0; e < 8; ++e) rowbase[e + 1] = rowbase[e] + rows[e];
    int totalRows = rowbase[8];
    int ebase[9];
    ebase[0] = 0;
    for (int e = 0; e < 8; ++e) ebase[e + 1] = ebase[e] + E[e];
    int totE = ebase[8];

    // ---- workspace: P(52), z(52), r, sb, sa, cnt(+1), bsum, rank, colind ----
    char* w = (char*)d_ws;
    size_t off = 0;
    auto alloc_f  = [&](size_t n) { float*  p = (float*)(w + off);  off += n * 4; return p; };
    auto alloc_f2 = [&](size_t n) { float2* p = (float2*)(w + off); off += n * 8; return p; };
    auto alloc_i  = [&](size_t n) { int*    p = (int*)(w + off);    off += n * 4; return p; };
    float* P[8]; for (int i = 0; i < 8; ++i) P[i] = alloc_f((size_t)nn[i] * PS);
    float* z[8]; for (int e = 0; e < 8; ++e) z[e] = alloc_f((size_t)rows[e] * PS);
    float* r[8]; for (int e = 0; e < 8; ++e) r[e] = alloc_f((size_t)rows[e] * 2);
    float2* sb[8]; for (int e = 0; e < 8; ++e) sb[e] = alloc_f2((size_t)ncol[e]);
    float2* sa[8]; for (int e = 0; e < 8; ++e) sa[e] = alloc_f2((size_t)rows[e]);
    int nScan = totalRows + 1;
    int* cnt = alloc_i((size_t)nScan);
    int nchunks = cdiv(nScan, 1024);
    int* bsum = alloc_i((size_t)nchunks);
    unsigned* rank = (unsigned*)alloc_i((size_t)totE);
    unsigned short* colind = (unsigned short*)(w + off);
    off += (size_t)totE * 2;
    (void)ws_size;

    const int B = 256;

    // ---- flat CSR build (single atomic pass) ----
    hipMemsetAsync(cnt, 0, (size_t)nScan * 4, stream);
    EdgeArgs EA;
    for (int e = 0; e < 8; ++e) {
        EA.rows[e] = edge[e]; EA.cols[e] = edge[e] + E[e];
        EA.rowbase[e] = rowbase[e];
        EA.ebase[e] = ebase[e];
    }
    EA.ebase[8] = ebase[8];
    EA.cnt = cnt; EA.rank = rank; EA.colind = colind;
    rank_kernel<<<cdiv(totE, B), B, 0, stream>>>(EA);
    scan_part_kernel<<<nchunks, 1024, 0, stream>>>(cnt, nScan, bsum);
    scan_bsum_kernel<<<1, 1024, 0, stream>>>(bsum, nchunks);
    add_off_kernel<<<nchunks, 1024, 0, stream>>>(cnt, nScan, bsum);
    place_kernel<<<cdiv(totE, B), B, 0, stream>>>(EA);  // cnt untouched: exclusive starts

    // ---- fac ----
    FacArgs FA;
    FA.base[0] = 0;
    for (int i = 0; i < 8; ++i) { FA.emb[i] = emb[i]; FA.P[i] = P[i]; FA.base[i + 1] = FA.base[i] + nn[i]; }
    FA.Wtk = Wtk;
    fac_kernel<<<cdiv(FA.base[8], B), B, 0, stream>>>(FA);

    // ---- static sb (rels 2..7) once ----
    SbArgs SBs;
    SBs.base[0] = 0;
    for (int e = 2; e < 8; ++e) {
        SBs.Pb[e - 2] = P[bIdx[e]];
        SBs.at[e - 2] = at + (size_t)e * KF * DD;
        SBs.sb[e - 2] = sb[e];
        SBs.base[e - 1] = SBs.base[e - 2] + ncol[e];
    }
    sb_kernel<<<cdiv(SBs.base[6], B), B, 0, stream>>>(SBs);

    // ---- initial dynamic scores (sa all rels + sb0/sb1) ----
    ScoreArgs SC;
    SC.P0 = P[0]; SC.P1 = P[1]; SC.at = at;
    for (int e = 0; e < 8; ++e) SC.sa[e] = sa[e];
    SC.sb0 = sb[0]; SC.sb1 = sb[1];
    SC.n0 = nn[0]; SC.n1 = nn[1];
    score01_kernel<<<cdiv(nn[0] + nn[1], B), B, 0, stream>>>(SC);

    // ---- iterations ----
    PhaseArgs PA;
    PA.rowptr = cnt; PA.colind = colind;
    for (int e = 0; e < 8; ++e) {
        PA.Pb[e] = P[bIdx[e]];
        PA.q[e]  = q + (size_t)e * DK;
        PA.sa[e] = sa[e]; PA.sb[e] = sb[e];
        PA.z[e] = z[e]; PA.r[e] = r[e];
        PA.rowbase[e] = rowbase[e];
    }
    PA.rowbase[8] = rowbase[8];
    PA.W = W;
    EgoArgs GA;
    GA.P0 = P[0]; GA.P1 = P[1]; GA.n0 = nn[0]; GA.n1 = nn[1];
    for (int e = 0; e < 8; ++e) { GA.zz[e] = z[e]; GA.rr[e] = r[e]; GA.sa[e] = sa[e]; }
    GA.at = at;
    GA.sb0 = sb[0]; GA.sb1 = sb[1];
    GA.outp = nullptr;

    for (int it = 0; it < ITERS; ++it) {
        phase_kernel<<<cdiv(totalRows, WPB), WPB * 64, 0, stream>>>(PA, totalRows);
        GA.outp = (it == ITERS - 1) ? out : nullptr;
        ego_kernel<<<cdiv(nn[0] + nn[1], B), B, 0, stream>>>(GA);
    }
}